// Round 2
// baseline (378.048 us; speedup 1.0000x reference)
//
#include <hip/hip_runtime.h>
#include <stdint.h>

// VQ-VAE vector quantizer — fp32, NCHW input [64,64,32,32], emb [1024,64].
// r19: r17's proven sweep core (ballot + col==0 extraction, depth-2 E
// prefetch) restored verbatim; occupancy fix: 512-thread blocks (8 waves,
// each sweeping a 128-code eighth) -> 32 waves/CU (was grid-limited 16).
// x-tile staged once in LDS (coalesced float4): fp32 xs[d][p] feeds exact-A
// partials / rescue / epilogue; bf16 swizzled xb[p][d] feeds fragments via
// 8x ds_read_b128 (was 64 scalar global loads + 192 convert VALU ops).
// Loss path bit-identical to r17 (tid<256 epilogue/fin, same trees).
constexpr int KCODES = 1024;
constexpr int DDIM   = 64;
constexpr int HW     = 1024;
constexpr int NPTS   = 65536;
constexpr int PPB    = 64;            // points per block
constexpr int NBLK   = NPTS / PPB;    // 1024

constexpr int OUT_IDX  = 4194304;
constexpr int OUT_LOSS = 4259840;
constexpr int OUT_NLL  = 4259841;

// ws 32-bit-unit offsets
constexpr int WS_MAXC  = 0;       // 16 f  : per-init-block max C
constexpr int WS_C     = 16;      // 1024 f: exact np C_k
constexpr int WS_E     = 2048;    // 32768 u32: SWIZZLED bf16-E (64 chunks x 2KB)
constexpr int WS_PART  = 34816;   // 1024 f: per-block loss partials
constexpr int WS_CTR   = 35840;   // 1 u32 : done-counter for fin merge

constexpr int XS_STR = 65;        // xs row stride (floats)

typedef __attribute__((ext_vector_type(8))) short short8v;
typedef __attribute__((ext_vector_type(4))) float float4v;

__device__ __forceinline__ uint16_t f2bf(float f) {   // RNE fp32->bf16
    uint32_t u = __float_as_uint(f);
    return (uint16_t)((u + 0x7fffu + ((u >> 16) & 1u)) >> 16);
}
__device__ __forceinline__ uint32_t pack2bf(float a, float b) {
    return (uint32_t)f2bf(a) | ((uint32_t)f2bf(b) << 16);
}

__device__ __forceinline__ float np_pairwise_sumsq64(const float* a) {
    float r[8];
    #pragma unroll
    for (int j = 0; j < 8; ++j) r[j] = __fmul_rn(a[j], a[j]);
    #pragma unroll
    for (int i = 8; i < 64; i += 8)
        #pragma unroll
        for (int j = 0; j < 8; ++j)
            r[j] = __fadd_rn(r[j], __fmul_rn(a[i + j], a[i + j]));
    return __fadd_rn(__fadd_rn(__fadd_rn(r[0], r[1]), __fadd_rn(r[2], r[3])),
                     __fadd_rn(__fadd_rn(r[4], r[5]), __fadd_rn(r[6], r[7])));
}

// 16 blocks x 64 threads: code k = blockIdx*64 + tid. Writes SWIZZLED E.
__global__ __launch_bounds__(64) void vq_init(const float* __restrict__ emb,
                                              float* __restrict__ ws) {
    const int k = blockIdx.x * 64 + threadIdx.x;
    float row[DDIM];
    const float4* src = (const float4*)(emb + (size_t)k * DDIM);
    #pragma unroll
    for (int j = 0; j < 16; ++j) ((float4*)row)[j] = src[j];
    float C = np_pairwise_sumsq64(row);
    ws[WS_C + k] = C;
    {
        const int c = k >> 4, col = k & 15;
        uint32_t* eb = (uint32_t*)ws + WS_E + c * 512;   // chunk base (u32)
        #pragma unroll
        for (int q = 0; q < 4; ++q) {
            uint32_t* d0 = eb + (q * 16 + col) * 4;          // b0 plane
            uint32_t* d1 = eb + 256 + (q * 16 + col) * 4;    // b1 plane
            #pragma unroll
            for (int j = 0; j < 4; ++j) {
                d0[j] = pack2bf(row[q * 8 + 2 * j],      row[q * 8 + 2 * j + 1]);
                d1[j] = pack2bf(row[32 + q * 8 + 2 * j], row[32 + q * 8 + 2 * j + 1]);
            }
        }
    }
    float m = C;
    #pragma unroll
    for (int off = 32; off > 0; off >>= 1) m = fmaxf(m, __shfl_down(m, off, 64));
    if (threadIdx.x == 0) ws[WS_MAXC + blockIdx.x] = m;
    if (k == 0) ((uint32_t*)ws)[WS_CTR] = 0u;
}

__global__ __launch_bounds__(512, 8) void vq_main(
        const float* __restrict__ inp, const float* __restrict__ emb,
        float* __restrict__ ws, float* __restrict__ out)
{
    __shared__ float    xs[DDIM * XS_STR];   // fp32 x-tile [d][p], stride 65
    __shared__ uint4    xb4[PPB * 8];        // bf16 x-tile [p][d], 16B swizzled
    __shared__ float    sAp[PPB][8];         // np r[j] slot partials
    __shared__ float    sA[PPB];
    __shared__ float    sPart[8][PPB];
    __shared__ float    sThr[PPB];
    __shared__ uint16_t sCand[PPB * 8 * 8];
    __shared__ uint8_t  sCnt[PPB * 8];
    __shared__ int      sWin[PPB];
    __shared__ float    sred[4];
    __shared__ int      sLast;

    const int tid  = threadIdx.x;
    const int lane = tid & 63;
    const int wave = tid >> 6;          // = code eighth (0..7)
    const int col  = lane & 15;
    const int quad = lane >> 4;
    const int base = blockIdx.x * PPB;
    const int b    = base >> 10;
    const int hw0  = base & 1023;

    const float* xg = inp + (size_t)b * DDIM * HW + hw0;

    // ---- stage fp32 x-tile, fully coalesced (2 float4 loads/thread) -------
    {
        const int f4 = tid & 15;
        #pragma unroll
        for (int it = 0; it < 2; ++it) {
            const int d = (tid >> 4) + it * 32;
            float4 v = *(const float4*)(xg + (size_t)d * HW + f4 * 4);
            float* dst = &xs[d * XS_STR + f4 * 4];
            dst[0] = v.x; dst[1] = v.y; dst[2] = v.z; dst[3] = v.w;
        }
    }
    __syncthreads();

    // ---- one-pass bf16 transpose-pack (swizzled) + exact-A slot partials --
    {
        const int p = tid >> 3, seg = tid & 7;
        uint32_t w0 = pack2bf(xs[(seg * 8 + 0) * XS_STR + p],
                              xs[(seg * 8 + 1) * XS_STR + p]);
        uint32_t w1 = pack2bf(xs[(seg * 8 + 2) * XS_STR + p],
                              xs[(seg * 8 + 3) * XS_STR + p]);
        uint32_t w2 = pack2bf(xs[(seg * 8 + 4) * XS_STR + p],
                              xs[(seg * 8 + 5) * XS_STR + p]);
        uint32_t w3 = pack2bf(xs[(seg * 8 + 6) * XS_STR + p],
                              xs[(seg * 8 + 7) * XS_STR + p]);
        xb4[p * 8 + (seg ^ (p & 7))] = make_uint4(w0, w1, w2, w3);

        // np slot j = seg: r_j = sum_i x[8i+j]^2, sequential (bit-exact)
        float v = xs[seg * XS_STR + p];
        float r = __fmul_rn(v, v);
        #pragma unroll
        for (int i = 1; i < 8; ++i) {
            float vv = xs[(8 * i + seg) * XS_STR + p];
            r = __fadd_rn(r, __fmul_rn(vv, vv));
        }
        sAp[p][seg] = r;
    }
    __syncthreads();

    // ---- X-fragments: 8x ds_read_b128 from swizzled xb (no converts) ------
    short8v a[4][2];
    {
        const short8v* xbv = (const short8v*)xb4;
        #pragma unroll
        for (int g = 0; g < 4; ++g) {
            const int row = g * 16 + col;
            const int sw  = row & 7;
            a[g][0] = xbv[row * 8 + ((0 + quad) ^ sw)];   // d = quad*8+j
            a[g][1] = xbv[row * 8 + ((4 + quad) ^ sw)];   // d = 32+quad*8+j
        }
    }

    // swizzled E: wave w reads chunks 8w..8w+7 (codes 128w..128w+127);
    // lane reads its 16B at chunk*2048 + plane*1024 + lane*16.
    const char* Eb = (const char*)((const uint32_t*)ws + WS_E);
    const char* Ew = Eb + (size_t)wave * 8 * 2048 + (size_t)lane * 16;
    const float* Cw = ws + WS_C;
    const int k0 = wave * 128;

    // ---- sweep 1: per-point score-max, depth-2 pipelined loads -------------
    float smaxv[4][4];
    #pragma unroll
    for (int g = 0; g < 4; ++g)
        #pragma unroll
        for (int r = 0; r < 4; ++r) smaxv[g][r] = -3.0e38f;

    {
        short8v pa0 = *(const short8v*)(Ew);
        short8v pa1 = *(const short8v*)(Ew + 1024);
        short8v pb0 = *(const short8v*)(Ew + 2048);
        short8v pb1 = *(const short8v*)(Ew + 3072);
        float   cia = Cw[k0 + col] * -0.5f;
        float   cib = Cw[k0 + 16 + col] * -0.5f;
        #pragma unroll 1
        for (int c2 = 0; c2 < 8; c2 += 2) {
            short8v u0 = pa0, u1 = pa1; float uci = cia;
            if (c2 + 2 < 8) {
                const char* er = Ew + (size_t)(c2 + 2) * 2048;
                pa0 = *(const short8v*)(er);
                pa1 = *(const short8v*)(er + 1024);
                cia = Cw[k0 + (c2 + 2) * 16 + col] * -0.5f;
            }
            float4v ci4 = {uci, uci, uci, uci};
            #pragma unroll
            for (int g = 0; g < 4; ++g) {
                float4v acc = ci4;
                acc = __builtin_amdgcn_mfma_f32_16x16x32_bf16(a[g][0], u0, acc, 0, 0, 0);
                acc = __builtin_amdgcn_mfma_f32_16x16x32_bf16(a[g][1], u1, acc, 0, 0, 0);
                #pragma unroll
                for (int r = 0; r < 4; ++r) smaxv[g][r] = fmaxf(smaxv[g][r], acc[r]);
            }
            short8v v0 = pb0, v1 = pb1; float vci = cib;
            if (c2 + 3 < 8) {
                const char* er = Ew + (size_t)(c2 + 3) * 2048;
                pb0 = *(const short8v*)(er);
                pb1 = *(const short8v*)(er + 1024);
                cib = Cw[k0 + (c2 + 3) * 16 + col] * -0.5f;
            }
            float4v ci4b = {vci, vci, vci, vci};
            #pragma unroll
            for (int g = 0; g < 4; ++g) {
                float4v acc = ci4b;
                acc = __builtin_amdgcn_mfma_f32_16x16x32_bf16(a[g][0], v0, acc, 0, 0, 0);
                acc = __builtin_amdgcn_mfma_f32_16x16x32_bf16(a[g][1], v1, acc, 0, 0, 0);
                #pragma unroll
                for (int r = 0; r < 4; ++r) smaxv[g][r] = fmaxf(smaxv[g][r], acc[r]);
            }
        }
    }
    #pragma unroll
    for (int g = 0; g < 4; ++g)
        #pragma unroll
        for (int r = 0; r < 4; ++r) {
            float m = smaxv[g][r];
            m = fmaxf(m, __shfl_xor(m, 1, 16));
            m = fmaxf(m, __shfl_xor(m, 2, 16));
            m = fmaxf(m, __shfl_xor(m, 4, 16));
            m = fmaxf(m, __shfl_xor(m, 8, 16));
            if (col == 0) sPart[wave][g * 16 + quad * 4 + r] = m;
        }
    __syncthreads();

    // ---- per-point threshold (combine exact-A slots, np tree) --------------
    if (tid < PPB) {
        float A = __fadd_rn(
            __fadd_rn(__fadd_rn(sAp[tid][0], sAp[tid][1]),
                      __fadd_rn(sAp[tid][2], sAp[tid][3])),
            __fadd_rn(__fadd_rn(sAp[tid][4], sAp[tid][5]),
                      __fadd_rn(sAp[tid][6], sAp[tid][7])));
        sA[tid] = A;
        float gm = fmaxf(
            fmaxf(fmaxf(sPart[0][tid], sPart[1][tid]),
                  fmaxf(sPart[2][tid], sPart[3][tid])),
            fmaxf(fmaxf(sPart[4][tid], sPart[5][tid]),
                  fmaxf(sPart[6][tid], sPart[7][tid])));
        float mc = ws[WS_MAXC];
        #pragma unroll
        for (int j = 1; j < 16; ++j) mc = fmaxf(mc, ws[WS_MAXC + j]);
        sThr[tid] = gm - (0.015625f * sqrtf(A) * sqrtf(mc) + 6e-5f);
    }
    __syncthreads();

    float thr[4][4];
    #pragma unroll
    for (int g = 0; g < 4; ++g)
        #pragma unroll
        for (int r = 0; r < 4; ++r) thr[g][r] = sThr[g * 16 + quad * 4 + r];

    // ---- sweep 2: candidates (identical MFMA, depth-2 pipeline, ballot) ----
    int cnt[4][4];
    #pragma unroll
    for (int g = 0; g < 4; ++g)
        #pragma unroll
        for (int r = 0; r < 4; ++r) cnt[g][r] = 0;

    {
        short8v pa0 = *(const short8v*)(Ew);
        short8v pa1 = *(const short8v*)(Ew + 1024);
        short8v pb0 = *(const short8v*)(Ew + 2048);
        short8v pb1 = *(const short8v*)(Ew + 3072);
        float   cia = Cw[k0 + col] * -0.5f;
        float   cib = Cw[k0 + 16 + col] * -0.5f;
        #pragma unroll 1
        for (int c2 = 0; c2 < 8; c2 += 2) {
            short8v u0 = pa0, u1 = pa1; float uci = cia;
            if (c2 + 2 < 8) {
                const char* er = Ew + (size_t)(c2 + 2) * 2048;
                pa0 = *(const short8v*)(er);
                pa1 = *(const short8v*)(er + 1024);
                cia = Cw[k0 + (c2 + 2) * 16 + col] * -0.5f;
            }
            float4v ci4 = {uci, uci, uci, uci};
            #pragma unroll
            for (int g = 0; g < 4; ++g) {
                float4v acc = ci4;
                acc = __builtin_amdgcn_mfma_f32_16x16x32_bf16(a[g][0], u0, acc, 0, 0, 0);
                acc = __builtin_amdgcn_mfma_f32_16x16x32_bf16(a[g][1], u1, acc, 0, 0, 0);
                #pragma unroll
                for (int r = 0; r < 4; ++r) {
                    unsigned long long bm = __ballot(acc[r] >= thr[g][r]);
                    if (col == 0) {
                        unsigned gm = (unsigned)(bm >> (quad * 16)) & 0xffffu;
                        while (gm) {
                            int bit = __ffs(gm) - 1;
                            gm &= gm - 1;
                            int ct = cnt[g][r];
                            if (ct < 8)
                                sCand[((g * 16 + quad * 4 + r) * 8 + wave) * 8 + ct] =
                                    (uint16_t)(k0 + c2 * 16 + bit);
                            cnt[g][r] = ct + 1;
                        }
                    }
                }
            }
            short8v v0 = pb0, v1 = pb1; float vci = cib;
            if (c2 + 3 < 8) {
                const char* er = Ew + (size_t)(c2 + 3) * 2048;
                pb0 = *(const short8v*)(er);
                pb1 = *(const short8v*)(er + 1024);
                cib = Cw[k0 + (c2 + 3) * 16 + col] * -0.5f;
            }
            float4v ci4b = {vci, vci, vci, vci};
            #pragma unroll
            for (int g = 0; g < 4; ++g) {
                float4v acc = ci4b;
                acc = __builtin_amdgcn_mfma_f32_16x16x32_bf16(a[g][0], v0, acc, 0, 0, 0);
                acc = __builtin_amdgcn_mfma_f32_16x16x32_bf16(a[g][1], v1, acc, 0, 0, 0);
                #pragma unroll
                for (int r = 0; r < 4; ++r) {
                    unsigned long long bm = __ballot(acc[r] >= thr[g][r]);
                    if (col == 0) {
                        unsigned gm = (unsigned)(bm >> (quad * 16)) & 0xffffu;
                        while (gm) {
                            int bit = __ffs(gm) - 1;
                            gm &= gm - 1;
                            int ct = cnt[g][r];
                            if (ct < 8)
                                sCand[((g * 16 + quad * 4 + r) * 8 + wave) * 8 + ct] =
                                    (uint16_t)(k0 + (c2 + 1) * 16 + bit);
                            cnt[g][r] = ct + 1;
                        }
                    }
                }
            }
        }
    }
    if (col == 0) {
        #pragma unroll
        for (int g = 0; g < 4; ++g)
            #pragma unroll
            for (int r = 0; r < 4; ++r) {
                int c = cnt[g][r];
                sCnt[(g * 16 + quad * 4 + r) * 8 + wave] = (uint8_t)(c > 255 ? 255 : c);
            }
    }
    __syncthreads();

    // ---- rescue: exact np-fp32 on candidates (x from LDS) ------------------
    if (tid < PPB) {
        const int p = tid, n = base + p;
        int tot = 0, cmaxc = 0;
        #pragma unroll
        for (int wq = 0; wq < 8; ++wq) {
            int c = sCnt[p * 8 + wq];
            tot += c;
            cmaxc = c > cmaxc ? c : cmaxc;
        }
        int win;
        if (tot == 1) {
            win = 0;
            #pragma unroll
            for (int wq = 0; wq < 8; ++wq)
                if (sCnt[p * 8 + wq]) win = sCand[(p * 8 + wq) * 8];
        } else {
            const float A = sA[p];
            float bd = 3.0e38f; win = KCODES - 1;
            if (cmaxc <= 8) {
                #pragma unroll 1
                for (int wq = 0; wq < 8; ++wq) {
                    int c = sCnt[p * 8 + wq];
                    #pragma unroll 1
                    for (int i = 0; i < c; ++i) {   // ascending k order
                        int k = sCand[(p * 8 + wq) * 8 + i];
                        const float4* e4 = (const float4*)(emb + (size_t)k * DDIM);
                        float g = 0.f;
                        #pragma unroll
                        for (int j = 0; j < 16; ++j) {
                            float4 ev = e4[j];
                            g = fmaf(xs[(4 * j + 0) * XS_STR + p], ev.x, g);
                            g = fmaf(xs[(4 * j + 1) * XS_STR + p], ev.y, g);
                            g = fmaf(xs[(4 * j + 2) * XS_STR + p], ev.z, g);
                            g = fmaf(xs[(4 * j + 3) * XS_STR + p], ev.w, g);
                        }
                        float dd = __fadd_rn(__fsub_rn(A, __fmul_rn(2.0f, g)), Cw[k]);
                        if (dd < bd || (dd == bd && k < win)) { bd = dd; win = k; }
                    }
                }
            } else {                                    // overflow safety
                #pragma unroll 1
                for (int k = 0; k < KCODES; ++k) {
                    const float4* e4 = (const float4*)(emb + (size_t)k * DDIM);
                    float g = 0.f;
                    #pragma unroll
                    for (int j = 0; j < 16; ++j) {
                        float4 ev = e4[j];
                        g = fmaf(xs[(4 * j + 0) * XS_STR + p], ev.x, g);
                        g = fmaf(xs[(4 * j + 1) * XS_STR + p], ev.y, g);
                        g = fmaf(xs[(4 * j + 2) * XS_STR + p], ev.z, g);
                        g = fmaf(xs[(4 * j + 3) * XS_STR + p], ev.w, g);
                    }
                    float dd = __fadd_rn(__fsub_rn(A, __fmul_rn(2.0f, g)), Cw[k]);
                    if (dd < bd) { bd = dd; win = k; }
                }
            }
        }
        sWin[p] = win;
        out[OUT_IDX + n] = (float)win;
    }
    __syncthreads();

    // ---- epilogue: quantized NCHW + loss partial (r17 mapping, tid<256) ----
    if (tid < 256) {
        const int pl = tid & 63, qtr = tid >> 6;
        const int win = sWin[pl];
        const int ch0 = qtr * 16;
        float q[16];
        const float4* q4 = (const float4*)(emb + (size_t)win * DDIM + ch0);
        #pragma unroll
        for (int j = 0; j < 4; ++j) ((float4*)q)[j] = q4[j];
        const size_t off = (size_t)b * DDIM * HW + (size_t)ch0 * HW + (hw0 + pl);
        float* orow = out + off;
        float lacc = 0.f;
        #pragma unroll
        for (int j = 0; j < 16; ++j) {
            float xv = xs[(ch0 + j) * XS_STR + pl];
            float diff = __fsub_rn(q[j], xv);
            orow[(size_t)j * HW] = __fadd_rn(xv, diff);   // ref's x + (q - x)
            lacc = fmaf(diff, diff, lacc);
        }
        #pragma unroll
        for (int o2 = 32; o2 > 0; o2 >>= 1) lacc += __shfl_down(lacc, o2, 64);
        if (lane == 0) sred[qtr] = lacc;
    }
    __syncthreads();

    // ---- fin merged: last block reduces partials (identical add order) -----
    if (tid == 0) {
        ws[WS_PART + blockIdx.x] = sred[0] + sred[1] + sred[2] + sred[3];
        __threadfence();
        unsigned int old = atomicAdd((unsigned int*)ws + WS_CTR, 1u);
        sLast = (old == NBLK - 1) ? 1 : 0;
    }
    __syncthreads();
    if (sLast) {
        __threadfence();
        if (tid < 256) {
            float s = 0.f;
            #pragma unroll
            for (int j = 0; j < 4; ++j) s += ws[WS_PART + j * 256 + tid];
            #pragma unroll
            for (int off = 32; off > 0; off >>= 1) s += __shfl_down(s, off, 64);
            if ((tid & 63) == 0) sred[tid >> 6] = s;
        }
        __syncthreads();
        if (tid == 0) {
            float L = sred[0] + sred[1] + sred[2] + sred[3];
            out[OUT_LOSS] = L * (1.25f / 4194304.0f);   // (1+CC)*mean over N*D
            out[OUT_NLL]  = 1.0f;
        }
    }
}

extern "C" void kernel_launch(void* const* d_in, const int* in_sizes, int n_in,
                              void* d_out, int out_size, void* d_ws, size_t ws_size,
                              hipStream_t stream) {
    const float* inp = (const float*)d_in[0];
    const float* emb = (const float*)d_in[1];
    float* out = (float*)d_out;
    float* ws  = (float*)d_ws;

    vq_init<<<16, 64, 0, stream>>>(emb, ws);
    vq_main<<<NBLK, 512, 0, stream>>>(inp, emb, ws, out);
}

// Round 3
// 165.107 us; speedup vs baseline: 2.2897x; 2.2897x over previous
//
#include <hip/hip_runtime.h>
#include <stdint.h>

// VQ-VAE vector quantizer — fp32, NCHW input [64,64,32,32], emb [1024,64].
// r20: occupancy via MORE blocks, same block shape. vq_argmin: PPB=32,
// grid 2048, 256 thr / 4 waves, __launch_bounds__(256,4) — the exact r17
// config that compiled to 64 VGPR with zero spill (r19's 512-thr + bound(8)
// forced VGPR=32 -> 900MB scratch traffic). Sweep core is r17 verbatim with
// g-range 2. Quantize+loss moved to vq_epi (1024 blocks, r17's epilogue +
// r19's merged fin — both absmax-0.0-proven) so the loss reduction tree is
// bit-identical; win indices round-trip через out[OUT_IDX] (exact in fp32).
constexpr int KCODES = 1024;
constexpr int DDIM   = 64;
constexpr int HW     = 1024;
constexpr int NPTS   = 65536;
constexpr int PPB    = 32;            // points per argmin block
constexpr int NBLK_A = NPTS / PPB;    // 2048
constexpr int EPB    = 64;            // points per epi block (r17 layout)
constexpr int NBLK_E = NPTS / EPB;    // 1024

constexpr int OUT_IDX  = 4194304;
constexpr int OUT_LOSS = 4259840;
constexpr int OUT_NLL  = 4259841;

// ws 32-bit-unit offsets
constexpr int WS_MAXC  = 0;       // 16 f  : per-init-block max C
constexpr int WS_C     = 16;      // 1024 f: exact np C_k
constexpr int WS_E     = 2048;    // 32768 u32: SWIZZLED bf16-E (64 chunks x 2KB)
constexpr int WS_PART  = 34816;   // 1024 f: per-block loss partials
constexpr int WS_CTR   = 35840;   // 1 u32 : done-counter for fin merge

typedef __attribute__((ext_vector_type(8))) short short8v;
typedef __attribute__((ext_vector_type(4))) float float4v;

__device__ __forceinline__ uint16_t f2bf(float f) {   // RNE fp32->bf16
    uint32_t u = __float_as_uint(f);
    return (uint16_t)((u + 0x7fffu + ((u >> 16) & 1u)) >> 16);
}
__device__ __forceinline__ uint32_t pack2bf(float a, float b) {
    return (uint32_t)f2bf(a) | ((uint32_t)f2bf(b) << 16);
}

__device__ __forceinline__ float np_pairwise_sumsq64(const float* a) {
    float r[8];
    #pragma unroll
    for (int j = 0; j < 8; ++j) r[j] = __fmul_rn(a[j], a[j]);
    #pragma unroll
    for (int i = 8; i < 64; i += 8)
        #pragma unroll
        for (int j = 0; j < 8; ++j)
            r[j] = __fadd_rn(r[j], __fmul_rn(a[i + j], a[i + j]));
    return __fadd_rn(__fadd_rn(__fadd_rn(r[0], r[1]), __fadd_rn(r[2], r[3])),
                     __fadd_rn(__fadd_rn(r[4], r[5]), __fadd_rn(r[6], r[7])));
}

// 16 blocks x 64 threads: code k = blockIdx*64 + tid. Writes SWIZZLED E.
__global__ __launch_bounds__(64) void vq_init(const float* __restrict__ emb,
                                              float* __restrict__ ws) {
    const int k = blockIdx.x * 64 + threadIdx.x;
    float row[DDIM];
    const float4* src = (const float4*)(emb + (size_t)k * DDIM);
    #pragma unroll
    for (int j = 0; j < 16; ++j) ((float4*)row)[j] = src[j];
    float C = np_pairwise_sumsq64(row);
    ws[WS_C + k] = C;
    {
        const int c = k >> 4, col = k & 15;
        uint32_t* eb = (uint32_t*)ws + WS_E + c * 512;   // chunk base (u32)
        #pragma unroll
        for (int q = 0; q < 4; ++q) {
            uint32_t* d0 = eb + (q * 16 + col) * 4;          // b0 plane
            uint32_t* d1 = eb + 256 + (q * 16 + col) * 4;    // b1 plane
            #pragma unroll
            for (int j = 0; j < 4; ++j) {
                d0[j] = pack2bf(row[q * 8 + 2 * j],      row[q * 8 + 2 * j + 1]);
                d1[j] = pack2bf(row[32 + q * 8 + 2 * j], row[32 + q * 8 + 2 * j + 1]);
            }
        }
    }
    float m = C;
    #pragma unroll
    for (int off = 32; off > 0; off >>= 1) m = fmaxf(m, __shfl_down(m, off, 64));
    if (threadIdx.x == 0) ws[WS_MAXC + blockIdx.x] = m;
    if (k == 0) ((uint32_t*)ws)[WS_CTR] = 0u;
}

// ---- argmin kernel: 2048 blocks x 256 thr, 32 points each -----------------
__global__ __launch_bounds__(256, 4) void vq_argmin(
        const float* __restrict__ inp, const float* __restrict__ emb,
        float* __restrict__ ws, float* __restrict__ out)
{
    __shared__ float    sAp[PPB][8];    // np 8-slot A partials
    __shared__ float    sA[PPB];
    __shared__ float    sPart[4][PPB];
    __shared__ float    sThr[PPB];
    __shared__ uint16_t sCand[PPB * 4 * 8];
    __shared__ uint8_t  sCnt[PPB * 4];

    const int tid  = threadIdx.x;
    const int lane = tid & 63;
    const int wave = tid >> 6;          // = code quarter
    const int col  = lane & 15;
    const int quad = lane >> 4;
    const int base = blockIdx.x * PPB;
    const int b    = base >> 10;
    const int hw0  = base & 1023;

    // ---- prologue: exact-A 8-slot partials (np tree; r19-verified split).
    //      p = tid&31 -> lanes contiguous in hw -> coalesced loads. ---------
    {
        const int pp  = tid & 31;           // point
        const int seg = tid >> 5;           // np slot j (0..7)
        const float* xin = inp + (size_t)b * DDIM * HW + (hw0 + pp);
        float v = xin[(size_t)seg * HW];
        float r = __fmul_rn(v, v);
        #pragma unroll
        for (int i = 1; i < 8; ++i) {
            float vv = xin[(size_t)(8 * i + seg) * HW];
            r = __fadd_rn(r, __fmul_rn(vv, vv));
        }
        sAp[pp][seg] = r;
    }

    // ---- X-fragments for 2 row-groups (r17-verified layout) ---------------
    short8v a[2][2];
    #pragma unroll
    for (int g = 0; g < 2; ++g) {
        const float* xp = inp + (size_t)b * DDIM * HW + (hw0 + g * 16 + col);
        short8v t0, t1;
        #pragma unroll
        for (int j = 0; j < 8; ++j) {
            t0[j] = (short)f2bf(xp[(size_t)(quad * 8 + j) * HW]);
            t1[j] = (short)f2bf(xp[(size_t)(32 + quad * 8 + j) * HW]);
        }
        a[g][0] = t0; a[g][1] = t1;
    }

    // swizzled E: lane reads its 16B at chunk*2048 + plane*1024 + lane*16 —
    // contiguous 1KB per wave-load (r17-proven).
    const char* Eb = (const char*)((const uint32_t*)ws + WS_E);
    const char* Ew = Eb + (size_t)wave * 16 * 2048 + (size_t)lane * 16;
    const float* Cw = ws + WS_C;
    const int k0 = wave * 256;

    // ---- sweep 1: per-point score-max, depth-2 pipelined loads -------------
    float smaxv[2][4];
    #pragma unroll
    for (int g = 0; g < 2; ++g)
        #pragma unroll
        for (int r = 0; r < 4; ++r) smaxv[g][r] = -3.0e38f;

    {
        short8v pa0 = *(const short8v*)(Ew);
        short8v pa1 = *(const short8v*)(Ew + 1024);
        short8v pb0 = *(const short8v*)(Ew + 2048);
        short8v pb1 = *(const short8v*)(Ew + 3072);
        float   cia = Cw[k0 + col] * -0.5f;
        float   cib = Cw[k0 + 16 + col] * -0.5f;
        #pragma unroll 1
        for (int c2 = 0; c2 < 16; c2 += 2) {
            short8v u0 = pa0, u1 = pa1; float uci = cia;
            if (c2 + 2 < 16) {
                const char* er = Ew + (size_t)(c2 + 2) * 2048;
                pa0 = *(const short8v*)(er);
                pa1 = *(const short8v*)(er + 1024);
                cia = Cw[k0 + (c2 + 2) * 16 + col] * -0.5f;
            }
            float4v ci4 = {uci, uci, uci, uci};
            #pragma unroll
            for (int g = 0; g < 2; ++g) {
                float4v acc = ci4;
                acc = __builtin_amdgcn_mfma_f32_16x16x32_bf16(a[g][0], u0, acc, 0, 0, 0);
                acc = __builtin_amdgcn_mfma_f32_16x16x32_bf16(a[g][1], u1, acc, 0, 0, 0);
                #pragma unroll
                for (int r = 0; r < 4; ++r) smaxv[g][r] = fmaxf(smaxv[g][r], acc[r]);
            }
            short8v v0 = pb0, v1 = pb1; float vci = cib;
            if (c2 + 3 < 16) {
                const char* er = Ew + (size_t)(c2 + 3) * 2048;
                pb0 = *(const short8v*)(er);
                pb1 = *(const short8v*)(er + 1024);
                cib = Cw[k0 + (c2 + 3) * 16 + col] * -0.5f;
            }
            float4v ci4b = {vci, vci, vci, vci};
            #pragma unroll
            for (int g = 0; g < 2; ++g) {
                float4v acc = ci4b;
                acc = __builtin_amdgcn_mfma_f32_16x16x32_bf16(a[g][0], v0, acc, 0, 0, 0);
                acc = __builtin_amdgcn_mfma_f32_16x16x32_bf16(a[g][1], v1, acc, 0, 0, 0);
                #pragma unroll
                for (int r = 0; r < 4; ++r) smaxv[g][r] = fmaxf(smaxv[g][r], acc[r]);
            }
        }
    }
    #pragma unroll
    for (int g = 0; g < 2; ++g)
        #pragma unroll
        for (int r = 0; r < 4; ++r) {
            float m = smaxv[g][r];
            m = fmaxf(m, __shfl_xor(m, 1, 16));
            m = fmaxf(m, __shfl_xor(m, 2, 16));
            m = fmaxf(m, __shfl_xor(m, 4, 16));
            m = fmaxf(m, __shfl_xor(m, 8, 16));
            if (col == 0) sPart[wave][g * 16 + quad * 4 + r] = m;
        }
    __syncthreads();

    // ---- per-point threshold (combine exact-A slots, np tree) --------------
    if (tid < PPB) {
        float A = __fadd_rn(
            __fadd_rn(__fadd_rn(sAp[tid][0], sAp[tid][1]),
                      __fadd_rn(sAp[tid][2], sAp[tid][3])),
            __fadd_rn(__fadd_rn(sAp[tid][4], sAp[tid][5]),
                      __fadd_rn(sAp[tid][6], sAp[tid][7])));
        sA[tid] = A;
        float gm = fmaxf(fmaxf(sPart[0][tid], sPart[1][tid]),
                         fmaxf(sPart[2][tid], sPart[3][tid]));
        float mc = ws[WS_MAXC];
        #pragma unroll
        for (int j = 1; j < 16; ++j) mc = fmaxf(mc, ws[WS_MAXC + j]);
        sThr[tid] = gm - (0.015625f * sqrtf(A) * sqrtf(mc) + 6e-5f);
    }
    __syncthreads();

    float thr[2][4];
    #pragma unroll
    for (int g = 0; g < 2; ++g)
        #pragma unroll
        for (int r = 0; r < 4; ++r) thr[g][r] = sThr[g * 16 + quad * 4 + r];

    // ---- sweep 2: candidates (identical MFMA, depth-2 pipeline, ballot) ----
    int cnt[2][4];
    #pragma unroll
    for (int g = 0; g < 2; ++g)
        #pragma unroll
        for (int r = 0; r < 4; ++r) cnt[g][r] = 0;

    {
        short8v pa0 = *(const short8v*)(Ew);
        short8v pa1 = *(const short8v*)(Ew + 1024);
        short8v pb0 = *(const short8v*)(Ew + 2048);
        short8v pb1 = *(const short8v*)(Ew + 3072);
        float   cia = Cw[k0 + col] * -0.5f;
        float   cib = Cw[k0 + 16 + col] * -0.5f;
        #pragma unroll 1
        for (int c2 = 0; c2 < 16; c2 += 2) {
            short8v u0 = pa0, u1 = pa1; float uci = cia;
            if (c2 + 2 < 16) {
                const char* er = Ew + (size_t)(c2 + 2) * 2048;
                pa0 = *(const short8v*)(er);
                pa1 = *(const short8v*)(er + 1024);
                cia = Cw[k0 + (c2 + 2) * 16 + col] * -0.5f;
            }
            float4v ci4 = {uci, uci, uci, uci};
            #pragma unroll
            for (int g = 0; g < 2; ++g) {
                float4v acc = ci4;
                acc = __builtin_amdgcn_mfma_f32_16x16x32_bf16(a[g][0], u0, acc, 0, 0, 0);
                acc = __builtin_amdgcn_mfma_f32_16x16x32_bf16(a[g][1], u1, acc, 0, 0, 0);
                #pragma unroll
                for (int r = 0; r < 4; ++r) {
                    unsigned long long bm = __ballot(acc[r] >= thr[g][r]);
                    if (col == 0) {
                        unsigned gm = (unsigned)(bm >> (quad * 16)) & 0xffffu;
                        while (gm) {
                            int bit = __ffs(gm) - 1;
                            gm &= gm - 1;
                            int ct = cnt[g][r];
                            if (ct < 8)
                                sCand[((g * 16 + quad * 4 + r) * 4 + wave) * 8 + ct] =
                                    (uint16_t)(k0 + c2 * 16 + bit);
                            cnt[g][r] = ct + 1;
                        }
                    }
                }
            }
            short8v v0 = pb0, v1 = pb1; float vci = cib;
            if (c2 + 3 < 16) {
                const char* er = Ew + (size_t)(c2 + 3) * 2048;
                pb0 = *(const short8v*)(er);
                pb1 = *(const short8v*)(er + 1024);
                cib = Cw[k0 + (c2 + 3) * 16 + col] * -0.5f;
            }
            float4v ci4b = {vci, vci, vci, vci};
            #pragma unroll
            for (int g = 0; g < 2; ++g) {
                float4v acc = ci4b;
                acc = __builtin_amdgcn_mfma_f32_16x16x32_bf16(a[g][0], v0, acc, 0, 0, 0);
                acc = __builtin_amdgcn_mfma_f32_16x16x32_bf16(a[g][1], v1, acc, 0, 0, 0);
                #pragma unroll
                for (int r = 0; r < 4; ++r) {
                    unsigned long long bm = __ballot(acc[r] >= thr[g][r]);
                    if (col == 0) {
                        unsigned gm = (unsigned)(bm >> (quad * 16)) & 0xffffu;
                        while (gm) {
                            int bit = __ffs(gm) - 1;
                            gm &= gm - 1;
                            int ct = cnt[g][r];
                            if (ct < 8)
                                sCand[((g * 16 + quad * 4 + r) * 4 + wave) * 8 + ct] =
                                    (uint16_t)(k0 + (c2 + 1) * 16 + bit);
                            cnt[g][r] = ct + 1;
                        }
                    }
                }
            }
        }
    }
    if (col == 0) {
        #pragma unroll
        for (int g = 0; g < 2; ++g)
            #pragma unroll
            for (int r = 0; r < 4; ++r) {
                int c = cnt[g][r];
                sCnt[(g * 16 + quad * 4 + r) * 4 + wave] = (uint8_t)(c > 255 ? 255 : c);
            }
    }
    __syncthreads();

    // ---- rescue: exact np-fp32 on candidates (r17 verbatim) ----------------
    if (tid < PPB) {
        const int p = tid, n = base + p;
        int cq[4], tot = 0, cmax = 0;
        #pragma unroll
        for (int q = 0; q < 4; ++q) {
            cq[q] = sCnt[p * 4 + q];
            tot += cq[q];
            cmax = cq[q] > cmax ? cq[q] : cmax;
        }
        int win;
        if (tot == 1) {
            win = 0;
            #pragma unroll
            for (int q = 0; q < 4; ++q)
                if (cq[q]) win = sCand[(p * 4 + q) * 8];
        } else {
            const float* xin = inp + (size_t)b * DDIM * HW + (hw0 + p);
            float x[DDIM];
            #pragma unroll
            for (int d = 0; d < DDIM; ++d) x[d] = xin[(size_t)d * HW];
            const float A = sA[p];
            float bd = 3.0e38f; win = KCODES - 1;
            if (cmax <= 8) {
                #pragma unroll 1
                for (int q = 0; q < 4; ++q) {
                    #pragma unroll 1
                    for (int i = 0; i < cq[q]; ++i) {   // ascending k order
                        int k = sCand[(p * 4 + q) * 8 + i];
                        float e[DDIM];
                        const float4* e4 = (const float4*)(emb + (size_t)k * DDIM);
                        #pragma unroll
                        for (int j = 0; j < 16; ++j) ((float4*)e)[j] = e4[j];
                        float g = 0.f;
                        #pragma unroll
                        for (int d = 0; d < DDIM; ++d) g = fmaf(x[d], e[d], g);
                        float dd = __fadd_rn(__fsub_rn(A, __fmul_rn(2.0f, g)), Cw[k]);
                        if (dd < bd || (dd == bd && k < win)) { bd = dd; win = k; }
                    }
                }
            } else {                                    // overflow safety
                #pragma unroll 1
                for (int k = 0; k < KCODES; ++k) {
                    float e[DDIM];
                    const float4* e4 = (const float4*)(emb + (size_t)k * DDIM);
                    #pragma unroll
                    for (int j = 0; j < 16; ++j) ((float4*)e)[j] = e4[j];
                    float g = 0.f;
                    #pragma unroll
                    for (int d = 0; d < DDIM; ++d) g = fmaf(x[d], e[d], g);
                    float dd = __fadd_rn(__fsub_rn(A, __fmul_rn(2.0f, g)), Cw[k]);
                    if (dd < bd) { bd = dd; win = k; }
                }
            }
        }
        out[OUT_IDX + n] = (float)win;
    }
}

// ---- epilogue kernel: quantized NCHW + loss (r17 epilogue + r19 fin) ------
__global__ __launch_bounds__(256, 4) void vq_epi(
        const float* __restrict__ inp, const float* __restrict__ emb,
        float* __restrict__ ws, float* __restrict__ out)
{
    __shared__ float sred[4];
    __shared__ int   sLast;

    const int tid  = threadIdx.x;
    const int lane = tid & 63;
    const int wave = tid >> 6;
    const int base = blockIdx.x * EPB;
    const int b    = base >> 10;
    const int hw0  = base & 1023;

    {
        const int pl = tid & 63, qtr = tid >> 6;
        const int win = (int)out[OUT_IDX + base + pl];
        const int ch0 = qtr * 16;
        float q[16];
        const float4* q4 = (const float4*)(emb + (size_t)win * DDIM + ch0);
        #pragma unroll
        for (int j = 0; j < 4; ++j) ((float4*)q)[j] = q4[j];
        const size_t off = (size_t)b * DDIM * HW + (size_t)ch0 * HW + (hw0 + pl);
        const float* xin2 = inp + off;
        float* orow = out + off;
        float lacc = 0.f;
        #pragma unroll
        for (int j = 0; j < 16; ++j) {
            float xv = xin2[(size_t)j * HW];
            float diff = __fsub_rn(q[j], xv);
            orow[(size_t)j * HW] = __fadd_rn(xv, diff);   // ref's x + (q - x)
            lacc = fmaf(diff, diff, lacc);
        }
        #pragma unroll
        for (int o2 = 32; o2 > 0; o2 >>= 1) lacc += __shfl_down(lacc, o2, 64);
        if (lane == 0) sred[wave] = lacc;
    }
    __syncthreads();

    if (tid == 0) {
        ws[WS_PART + blockIdx.x] = sred[0] + sred[1] + sred[2] + sred[3];
        __threadfence();
        unsigned int old = atomicAdd((unsigned int*)ws + WS_CTR, 1u);
        sLast = (old == NBLK_E - 1) ? 1 : 0;
    }
    __syncthreads();
    if (sLast) {
        __threadfence();
        float s = 0.f;
        #pragma unroll
        for (int j = 0; j < 4; ++j) s += ws[WS_PART + j * 256 + tid];
        #pragma unroll
        for (int off = 32; off > 0; off >>= 1) s += __shfl_down(s, off, 64);
        if ((tid & 63) == 0) sred[tid >> 6] = s;
        __syncthreads();
        if (tid == 0) {
            float L = sred[0] + sred[1] + sred[2] + sred[3];
            out[OUT_LOSS] = L * (1.25f / 4194304.0f);   // (1+CC)*mean over N*D
            out[OUT_NLL]  = 1.0f;
        }
    }
}

extern "C" void kernel_launch(void* const* d_in, const int* in_sizes, int n_in,
                              void* d_out, int out_size, void* d_ws, size_t ws_size,
                              hipStream_t stream) {
    const float* inp = (const float*)d_in[0];
    const float* emb = (const float*)d_in[1];
    float* out = (float*)d_out;
    float* ws  = (float*)d_ws;

    vq_init<<<16, 64, 0, stream>>>(emb, ws);
    vq_argmin<<<NBLK_A, 256, 0, stream>>>(inp, emb, ws, out);
    vq_epi<<<NBLK_E, 256, 0, stream>>>(inp, emb, ws, out);
}

// Round 4
// 148.938 us; speedup vs baseline: 2.5383x; 1.1086x over previous
//
#include <hip/hip_runtime.h>
#include <stdint.h>

// VQ-VAE vector quantizer — fp32, NCHW input [64,64,32,32], emb [1024,64].
// r21 = r17 verbatim core (1024 blk x 256 thr, bounds(256,4), g=4, PPB=64,
// ballot+col==0 sweep-2, depth-2 E prefetch — the 53us/absmax-0.0 config)
// + ONLY the r19/r20-verified staging swaps:
//   * xs fp32 x-tile in LDS, 4 coalesced float4 loads/thread (was 64+16
//     stride-4KB scalar loads/thread)
//   * xb4 swizzled bf16 x-tile -> fragments via 8x ds_read_b128, zero f2bf
//     in the build (was ~300 VALU ops/thread)
//   * A-partials / rescue dot / epilogue read xs (bit-exact np trees, r19/r20
//     absmax-0.0-proven)
//   * merged fin (r18/r19-proven), vq_init 16x64 (r19/r20-proven)
constexpr int KCODES = 1024;
constexpr int DDIM   = 64;
constexpr int HW     = 1024;
constexpr int NPTS   = 65536;
constexpr int PPB    = 64;            // points per block
constexpr int NBLK   = NPTS / PPB;    // 1024

constexpr int OUT_IDX  = 4194304;
constexpr int OUT_LOSS = 4259840;
constexpr int OUT_NLL  = 4259841;

// ws 32-bit-unit offsets
constexpr int WS_MAXC  = 0;       // 16 f  : per-init-block max C
constexpr int WS_C     = 16;      // 1024 f: exact np C_k
constexpr int WS_E     = 2048;    // 32768 u32: SWIZZLED bf16-E (64 chunks x 2KB)
constexpr int WS_PART  = 34816;   // 1024 f: per-block loss partials
constexpr int WS_CTR   = 35840;   // 1 u32 : done-counter for fin merge

constexpr int XS_STR = 65;        // xs row stride (floats)

typedef __attribute__((ext_vector_type(8))) short short8v;
typedef __attribute__((ext_vector_type(4))) float float4v;

__device__ __forceinline__ uint16_t f2bf(float f) {   // RNE fp32->bf16
    uint32_t u = __float_as_uint(f);
    return (uint16_t)((u + 0x7fffu + ((u >> 16) & 1u)) >> 16);
}
__device__ __forceinline__ uint32_t pack2bf(float a, float b) {
    return (uint32_t)f2bf(a) | ((uint32_t)f2bf(b) << 16);
}

__device__ __forceinline__ float np_pairwise_sumsq64(const float* a) {
    float r[8];
    #pragma unroll
    for (int j = 0; j < 8; ++j) r[j] = __fmul_rn(a[j], a[j]);
    #pragma unroll
    for (int i = 8; i < 64; i += 8)
        #pragma unroll
        for (int j = 0; j < 8; ++j)
            r[j] = __fadd_rn(r[j], __fmul_rn(a[i + j], a[i + j]));
    return __fadd_rn(__fadd_rn(__fadd_rn(r[0], r[1]), __fadd_rn(r[2], r[3])),
                     __fadd_rn(__fadd_rn(r[4], r[5]), __fadd_rn(r[6], r[7])));
}

// 16 blocks x 64 threads: code k = blockIdx*64 + tid. Writes SWIZZLED E.
__global__ __launch_bounds__(64) void vq_init(const float* __restrict__ emb,
                                              float* __restrict__ ws) {
    const int k = blockIdx.x * 64 + threadIdx.x;
    float row[DDIM];
    const float4* src = (const float4*)(emb + (size_t)k * DDIM);
    #pragma unroll
    for (int j = 0; j < 16; ++j) ((float4*)row)[j] = src[j];
    float C = np_pairwise_sumsq64(row);
    ws[WS_C + k] = C;
    {
        const int c = k >> 4, col = k & 15;
        uint32_t* eb = (uint32_t*)ws + WS_E + c * 512;   // chunk base (u32)
        #pragma unroll
        for (int q = 0; q < 4; ++q) {
            uint32_t* d0 = eb + (q * 16 + col) * 4;          // b0 plane
            uint32_t* d1 = eb + 256 + (q * 16 + col) * 4;    // b1 plane
            #pragma unroll
            for (int j = 0; j < 4; ++j) {
                d0[j] = pack2bf(row[q * 8 + 2 * j],      row[q * 8 + 2 * j + 1]);
                d1[j] = pack2bf(row[32 + q * 8 + 2 * j], row[32 + q * 8 + 2 * j + 1]);
            }
        }
    }
    float m = C;
    #pragma unroll
    for (int off = 32; off > 0; off >>= 1) m = fmaxf(m, __shfl_down(m, off, 64));
    if (threadIdx.x == 0) ws[WS_MAXC + blockIdx.x] = m;
    if (k == 0) ((uint32_t*)ws)[WS_CTR] = 0u;
}

__global__ __launch_bounds__(256, 4) void vq_main(
        const float* __restrict__ inp, const float* __restrict__ emb,
        float* __restrict__ ws, float* __restrict__ out)
{
    __shared__ float    xs[DDIM * XS_STR];   // fp32 x-tile [d][p], stride 65
    __shared__ uint4    xb4[PPB * 8];        // bf16 x-tile [p][chunk], swizzled
    __shared__ float    sAp[PPB][8];         // np 8-slot A partials
    __shared__ float    sA[PPB];
    __shared__ float    sPart[4][PPB];
    __shared__ float    sThr[PPB];
    __shared__ uint16_t sCand[PPB * 4 * 8];
    __shared__ uint8_t  sCnt[PPB * 4];
    __shared__ int      sWin[PPB];
    __shared__ float    sred[4];
    __shared__ int      sLast;

    const int tid  = threadIdx.x;
    const int lane = tid & 63;
    const int wave = tid >> 6;          // = code quarter
    const int col  = lane & 15;
    const int quad = lane >> 4;
    const int base = blockIdx.x * PPB;
    const int b    = base >> 10;
    const int hw0  = base & 1023;

    const float* xg = inp + (size_t)b * DDIM * HW + hw0;

    // ---- stage fp32 x-tile, fully coalesced (4 float4 loads/thread) -------
    {
        const int f4 = tid & 15;
        #pragma unroll
        for (int it = 0; it < 4; ++it) {
            const int d = (tid >> 4) + it * 16;
            float4 v = *(const float4*)(xg + (size_t)d * HW + f4 * 4);
            float* dst = &xs[d * XS_STR + f4 * 4];
            dst[0] = v.x; dst[1] = v.y; dst[2] = v.z; dst[3] = v.w;
        }
    }
    __syncthreads();

    // ---- bf16 transpose-pack (swizzled, r19-verified) + exact-A partials --
    //      thread (p = tid&63, j = tid>>6) handles chunks/slots j and j+4.
    {
        const int p = tid & 63, j0 = tid >> 6;
        #pragma unroll
        for (int h = 0; h < 2; ++h) {
            const int seg = j0 + h * 4;
            uint32_t w0 = pack2bf(xs[(seg * 8 + 0) * XS_STR + p],
                                  xs[(seg * 8 + 1) * XS_STR + p]);
            uint32_t w1 = pack2bf(xs[(seg * 8 + 2) * XS_STR + p],
                                  xs[(seg * 8 + 3) * XS_STR + p]);
            uint32_t w2 = pack2bf(xs[(seg * 8 + 4) * XS_STR + p],
                                  xs[(seg * 8 + 5) * XS_STR + p]);
            uint32_t w3 = pack2bf(xs[(seg * 8 + 6) * XS_STR + p],
                                  xs[(seg * 8 + 7) * XS_STR + p]);
            xb4[p * 8 + (seg ^ (p & 7))] = make_uint4(w0, w1, w2, w3);

            // np slot seg: r_seg = sum_i x[8i+seg]^2, sequential (bit-exact)
            float v = xs[seg * XS_STR + p];
            float r = __fmul_rn(v, v);
            #pragma unroll
            for (int i = 1; i < 8; ++i) {
                float vv = xs[(8 * i + seg) * XS_STR + p];
                r = __fadd_rn(r, __fmul_rn(vv, vv));
            }
            sAp[p][seg] = r;
        }
    }
    __syncthreads();

    // ---- X-fragments: 8x ds_read_b128 from swizzled xb4 (r19-verified) ----
    short8v a[4][2];
    {
        const short8v* xbv = (const short8v*)xb4;
        #pragma unroll
        for (int g = 0; g < 4; ++g) {
            const int row = g * 16 + col;
            const int sw  = row & 7;
            a[g][0] = xbv[row * 8 + (quad ^ sw)];         // d = quad*8 + j
            a[g][1] = xbv[row * 8 + ((4 + quad) ^ sw)];   // d = 32 + quad*8 + j
        }
    }

    // swizzled E: lane reads its 16B at chunk*2048 + plane*1024 + lane*16 —
    // contiguous 1KB per wave-load (r17-proven 15% win).
    const char* Eb = (const char*)((const uint32_t*)ws + WS_E);
    const char* Ew = Eb + (size_t)wave * 16 * 2048 + (size_t)lane * 16;
    const float* Cw = ws + WS_C;
    const int k0 = wave * 256;

    // ---- sweep 1: per-point score-max, depth-2 pipelined loads -------------
    float smaxv[4][4];
    #pragma unroll
    for (int g = 0; g < 4; ++g)
        #pragma unroll
        for (int r = 0; r < 4; ++r) smaxv[g][r] = -3.0e38f;

    {
        short8v pa0 = *(const short8v*)(Ew);
        short8v pa1 = *(const short8v*)(Ew + 1024);
        short8v pb0 = *(const short8v*)(Ew + 2048);
        short8v pb1 = *(const short8v*)(Ew + 3072);
        float   cia = Cw[k0 + col] * -0.5f;
        float   cib = Cw[k0 + 16 + col] * -0.5f;
        #pragma unroll 1
        for (int c2 = 0; c2 < 16; c2 += 2) {
            short8v u0 = pa0, u1 = pa1; float uci = cia;
            if (c2 + 2 < 16) {
                const char* er = Ew + (size_t)(c2 + 2) * 2048;
                pa0 = *(const short8v*)(er);
                pa1 = *(const short8v*)(er + 1024);
                cia = Cw[k0 + (c2 + 2) * 16 + col] * -0.5f;
            }
            float4v ci4 = {uci, uci, uci, uci};
            #pragma unroll
            for (int g = 0; g < 4; ++g) {
                float4v acc = ci4;
                acc = __builtin_amdgcn_mfma_f32_16x16x32_bf16(a[g][0], u0, acc, 0, 0, 0);
                acc = __builtin_amdgcn_mfma_f32_16x16x32_bf16(a[g][1], u1, acc, 0, 0, 0);
                #pragma unroll
                for (int r = 0; r < 4; ++r) smaxv[g][r] = fmaxf(smaxv[g][r], acc[r]);
            }
            short8v v0 = pb0, v1 = pb1; float vci = cib;
            if (c2 + 3 < 16) {
                const char* er = Ew + (size_t)(c2 + 3) * 2048;
                pb0 = *(const short8v*)(er);
                pb1 = *(const short8v*)(er + 1024);
                cib = Cw[k0 + (c2 + 3) * 16 + col] * -0.5f;
            }
            float4v ci4b = {vci, vci, vci, vci};
            #pragma unroll
            for (int g = 0; g < 4; ++g) {
                float4v acc = ci4b;
                acc = __builtin_amdgcn_mfma_f32_16x16x32_bf16(a[g][0], v0, acc, 0, 0, 0);
                acc = __builtin_amdgcn_mfma_f32_16x16x32_bf16(a[g][1], v1, acc, 0, 0, 0);
                #pragma unroll
                for (int r = 0; r < 4; ++r) smaxv[g][r] = fmaxf(smaxv[g][r], acc[r]);
            }
        }
    }
    #pragma unroll
    for (int g = 0; g < 4; ++g)
        #pragma unroll
        for (int r = 0; r < 4; ++r) {
            float m = smaxv[g][r];
            m = fmaxf(m, __shfl_xor(m, 1, 16));
            m = fmaxf(m, __shfl_xor(m, 2, 16));
            m = fmaxf(m, __shfl_xor(m, 4, 16));
            m = fmaxf(m, __shfl_xor(m, 8, 16));
            if (col == 0) sPart[wave][g * 16 + quad * 4 + r] = m;
        }
    __syncthreads();

    // ---- per-point threshold (combine exact-A 8 slots, np tree) ------------
    if (tid < PPB) {
        float A = __fadd_rn(
            __fadd_rn(__fadd_rn(sAp[tid][0], sAp[tid][1]),
                      __fadd_rn(sAp[tid][2], sAp[tid][3])),
            __fadd_rn(__fadd_rn(sAp[tid][4], sAp[tid][5]),
                      __fadd_rn(sAp[tid][6], sAp[tid][7])));
        sA[tid] = A;
        float gm = fmaxf(fmaxf(sPart[0][tid], sPart[1][tid]),
                         fmaxf(sPart[2][tid], sPart[3][tid]));
        float mc = ws[WS_MAXC];
        #pragma unroll
        for (int j = 1; j < 16; ++j) mc = fmaxf(mc, ws[WS_MAXC + j]);
        sThr[tid] = gm - (0.015625f * sqrtf(A) * sqrtf(mc) + 6e-5f);
    }
    __syncthreads();

    float thr[4][4];
    #pragma unroll
    for (int g = 0; g < 4; ++g)
        #pragma unroll
        for (int r = 0; r < 4; ++r) thr[g][r] = sThr[g * 16 + quad * 4 + r];

    // ---- sweep 2: candidates (identical MFMA, depth-2 pipeline, ballot) ----
    int cnt[4][4];
    #pragma unroll
    for (int g = 0; g < 4; ++g)
        #pragma unroll
        for (int r = 0; r < 4; ++r) cnt[g][r] = 0;

    {
        short8v pa0 = *(const short8v*)(Ew);
        short8v pa1 = *(const short8v*)(Ew + 1024);
        short8v pb0 = *(const short8v*)(Ew + 2048);
        short8v pb1 = *(const short8v*)(Ew + 3072);
        float   cia = Cw[k0 + col] * -0.5f;
        float   cib = Cw[k0 + 16 + col] * -0.5f;
        #pragma unroll 1
        for (int c2 = 0; c2 < 16; c2 += 2) {
            short8v u0 = pa0, u1 = pa1; float uci = cia;
            if (c2 + 2 < 16) {
                const char* er = Ew + (size_t)(c2 + 2) * 2048;
                pa0 = *(const short8v*)(er);
                pa1 = *(const short8v*)(er + 1024);
                cia = Cw[k0 + (c2 + 2) * 16 + col] * -0.5f;
            }
            float4v ci4 = {uci, uci, uci, uci};
            #pragma unroll
            for (int g = 0; g < 4; ++g) {
                float4v acc = ci4;
                acc = __builtin_amdgcn_mfma_f32_16x16x32_bf16(a[g][0], u0, acc, 0, 0, 0);
                acc = __builtin_amdgcn_mfma_f32_16x16x32_bf16(a[g][1], u1, acc, 0, 0, 0);
                #pragma unroll
                for (int r = 0; r < 4; ++r) {
                    unsigned long long bm = __ballot(acc[r] >= thr[g][r]);
                    if (col == 0) {
                        unsigned gm = (unsigned)(bm >> (quad * 16)) & 0xffffu;
                        while (gm) {
                            int bit = __ffs(gm) - 1;
                            gm &= gm - 1;
                            int ct = cnt[g][r];
                            if (ct < 8)
                                sCand[((g * 16 + quad * 4 + r) * 4 + wave) * 8 + ct] =
                                    (uint16_t)(k0 + c2 * 16 + bit);
                            cnt[g][r] = ct + 1;
                        }
                    }
                }
            }
            short8v v0 = pb0, v1 = pb1; float vci = cib;
            if (c2 + 3 < 16) {
                const char* er = Ew + (size_t)(c2 + 3) * 2048;
                pb0 = *(const short8v*)(er);
                pb1 = *(const short8v*)(er + 1024);
                cib = Cw[k0 + (c2 + 3) * 16 + col] * -0.5f;
            }
            float4v ci4b = {vci, vci, vci, vci};
            #pragma unroll
            for (int g = 0; g < 4; ++g) {
                float4v acc = ci4b;
                acc = __builtin_amdgcn_mfma_f32_16x16x32_bf16(a[g][0], v0, acc, 0, 0, 0);
                acc = __builtin_amdgcn_mfma_f32_16x16x32_bf16(a[g][1], v1, acc, 0, 0, 0);
                #pragma unroll
                for (int r = 0; r < 4; ++r) {
                    unsigned long long bm = __ballot(acc[r] >= thr[g][r]);
                    if (col == 0) {
                        unsigned gm = (unsigned)(bm >> (quad * 16)) & 0xffffu;
                        while (gm) {
                            int bit = __ffs(gm) - 1;
                            gm &= gm - 1;
                            int ct = cnt[g][r];
                            if (ct < 8)
                                sCand[((g * 16 + quad * 4 + r) * 4 + wave) * 8 + ct] =
                                    (uint16_t)(k0 + (c2 + 1) * 16 + bit);
                            cnt[g][r] = ct + 1;
                        }
                    }
                }
            }
        }
    }
    if (col == 0) {
        #pragma unroll
        for (int g = 0; g < 4; ++g)
            #pragma unroll
            for (int r = 0; r < 4; ++r) {
                int c = cnt[g][r];
                sCnt[(g * 16 + quad * 4 + r) * 4 + wave] = (uint8_t)(c > 255 ? 255 : c);
            }
    }
    __syncthreads();

    // ---- rescue: exact np-fp32 on candidates (x from LDS, r19-verified) ----
    if (tid < PPB) {
        const int p = tid, n = base + p;
        int cq[4], tot = 0, cmax = 0;
        #pragma unroll
        for (int q = 0; q < 4; ++q) {
            cq[q] = sCnt[p * 4 + q];
            tot += cq[q];
            cmax = cq[q] > cmax ? cq[q] : cmax;
        }
        int win;
        if (tot == 1) {
            win = 0;
            #pragma unroll
            for (int q = 0; q < 4; ++q)
                if (cq[q]) win = sCand[(p * 4 + q) * 8];
        } else {
            const float A = sA[p];
            float bd = 3.0e38f; win = KCODES - 1;
            if (cmax <= 8) {
                #pragma unroll 1
                for (int q = 0; q < 4; ++q) {
                    #pragma unroll 1
                    for (int i = 0; i < cq[q]; ++i) {   // ascending k order
                        int k = sCand[(p * 4 + q) * 8 + i];
                        const float4* e4 = (const float4*)(emb + (size_t)k * DDIM);
                        float g = 0.f;
                        #pragma unroll
                        for (int j = 0; j < 16; ++j) {
                            float4 ev = e4[j];
                            g = fmaf(xs[(4 * j + 0) * XS_STR + p], ev.x, g);
                            g = fmaf(xs[(4 * j + 1) * XS_STR + p], ev.y, g);
                            g = fmaf(xs[(4 * j + 2) * XS_STR + p], ev.z, g);
                            g = fmaf(xs[(4 * j + 3) * XS_STR + p], ev.w, g);
                        }
                        float dd = __fadd_rn(__fsub_rn(A, __fmul_rn(2.0f, g)), Cw[k]);
                        if (dd < bd || (dd == bd && k < win)) { bd = dd; win = k; }
                    }
                }
            } else {                                    // overflow safety
                #pragma unroll 1
                for (int k = 0; k < KCODES; ++k) {
                    const float4* e4 = (const float4*)(emb + (size_t)k * DDIM);
                    float g = 0.f;
                    #pragma unroll
                    for (int j = 0; j < 16; ++j) {
                        float4 ev = e4[j];
                        g = fmaf(xs[(4 * j + 0) * XS_STR + p], ev.x, g);
                        g = fmaf(xs[(4 * j + 1) * XS_STR + p], ev.y, g);
                        g = fmaf(xs[(4 * j + 2) * XS_STR + p], ev.z, g);
                        g = fmaf(xs[(4 * j + 3) * XS_STR + p], ev.w, g);
                    }
                    float dd = __fadd_rn(__fsub_rn(A, __fmul_rn(2.0f, g)), Cw[k]);
                    if (dd < bd) { bd = dd; win = k; }
                }
            }
        }
        sWin[p] = win;
        out[OUT_IDX + n] = (float)win;
    }
    __syncthreads();

    // ---- epilogue: quantized NCHW + loss partial (xv from LDS) -------------
    {
        const int pl = tid & 63, qtr = tid >> 6;
        const int win = sWin[pl];
        const int ch0 = qtr * 16;
        float q[16];
        const float4* q4 = (const float4*)(emb + (size_t)win * DDIM + ch0);
        #pragma unroll
        for (int j = 0; j < 4; ++j) ((float4*)q)[j] = q4[j];
        const size_t off = (size_t)b * DDIM * HW + (size_t)ch0 * HW + (hw0 + pl);
        float* orow = out + off;
        float lacc = 0.f;
        #pragma unroll
        for (int j = 0; j < 16; ++j) {
            float xv = xs[(ch0 + j) * XS_STR + pl];
            float diff = __fsub_rn(q[j], xv);
            orow[(size_t)j * HW] = __fadd_rn(xv, diff);   // ref's x + (q - x)
            lacc = fmaf(diff, diff, lacc);
        }
        #pragma unroll
        for (int o2 = 32; o2 > 0; o2 >>= 1) lacc += __shfl_down(lacc, o2, 64);
        if (lane == 0) sred[wave] = lacc;
    }
    __syncthreads();

    // ---- fin merged: last block reduces partials (identical add order) -----
    if (tid == 0) {
        ws[WS_PART + blockIdx.x] = sred[0] + sred[1] + sred[2] + sred[3];
        __threadfence();
        unsigned int old = atomicAdd((unsigned int*)ws + WS_CTR, 1u);
        sLast = (old == NBLK - 1) ? 1 : 0;
    }
    __syncthreads();
    if (sLast) {
        __threadfence();
        float s = 0.f;
        #pragma unroll
        for (int j = 0; j < 4; ++j) s += ws[WS_PART + j * 256 + tid];
        #pragma unroll
        for (int off = 32; off > 0; off >>= 1) s += __shfl_down(s, off, 64);
        if ((tid & 63) == 0) sred[tid >> 6] = s;
        __syncthreads();
        if (tid == 0) {
            float L = sred[0] + sred[1] + sred[2] + sred[3];
            out[OUT_LOSS] = L * (1.25f / 4194304.0f);   // (1+CC)*mean over N*D
            out[OUT_NLL]  = 1.0f;
        }
    }
}

extern "C" void kernel_launch(void* const* d_in, const int* in_sizes, int n_in,
                              void* d_out, int out_size, void* d_ws, size_t ws_size,
                              hipStream_t stream) {
    const float* inp = (const float*)d_in[0];
    const float* emb = (const float*)d_in[1];
    float* out = (float*)d_out;
    float* ws  = (float*)d_ws;

    vq_init<<<16, 64, 0, stream>>>(emb, ws);
    vq_main<<<NBLK, 256, 0, stream>>>(inp, emb, ws, out);
}

// Round 5
// 148.182 us; speedup vs baseline: 2.5512x; 1.0051x over previous
//
#include <hip/hip_runtime.h>
#include <stdint.h>

// VQ-VAE vector quantizer — fp32, NCHW input [64,64,32,32], emb [1024,64].
// r22 = Round-0 (117.4us best) vq_main BYTE-IDENTICAL core: swizzled-E
// contiguous 1KB B-loads, direct-global fragment build, 4-thread exact-A
// prologue, ballot+col==0 sweep-2, depth-2 E prefetch, bounds(256,4).
// Only additions (both independently absmax-0.0-proven, off the core path):
//   * merged fin tail after the epilogue barrier (R1/R4) -> one less launch
//   * vq_init 16x64 (R1-R4) -> init off critical path
// R1/R2/R4 lesson: the r17 scheduling is delicate — no other changes.
constexpr int KCODES = 1024;
constexpr int DDIM   = 64;
constexpr int HW     = 1024;
constexpr int NPTS   = 65536;
constexpr int PPB    = 64;            // points per block
constexpr int NBLK   = NPTS / PPB;    // 1024

constexpr int OUT_IDX  = 4194304;
constexpr int OUT_LOSS = 4259840;
constexpr int OUT_NLL  = 4259841;

// ws 32-bit-unit offsets
constexpr int WS_MAXC  = 0;       // 16 f  : per-init-block max C
constexpr int WS_C     = 16;      // 1024 f: exact np C_k
constexpr int WS_E     = 2048;    // 32768 u32: SWIZZLED bf16-E (64 chunks x 2KB)
constexpr int WS_PART  = 34816;   // 1024 f: per-block loss partials
constexpr int WS_CTR   = 35840;   // 1 u32 : done-counter for fin merge

typedef __attribute__((ext_vector_type(8))) short short8v;
typedef __attribute__((ext_vector_type(4))) float float4v;

__device__ __forceinline__ uint16_t f2bf(float f) {   // RNE fp32->bf16
    uint32_t u = __float_as_uint(f);
    return (uint16_t)((u + 0x7fffu + ((u >> 16) & 1u)) >> 16);
}
__device__ __forceinline__ uint32_t pack2bf(float a, float b) {
    return (uint32_t)f2bf(a) | ((uint32_t)f2bf(b) << 16);
}

__device__ __forceinline__ float np_pairwise_sumsq64(const float* a) {
    float r[8];
    #pragma unroll
    for (int j = 0; j < 8; ++j) r[j] = __fmul_rn(a[j], a[j]);
    #pragma unroll
    for (int i = 8; i < 64; i += 8)
        #pragma unroll
        for (int j = 0; j < 8; ++j)
            r[j] = __fadd_rn(r[j], __fmul_rn(a[i + j], a[i + j]));
    return __fadd_rn(__fadd_rn(__fadd_rn(r[0], r[1]), __fadd_rn(r[2], r[3])),
                     __fadd_rn(__fadd_rn(r[4], r[5]), __fadd_rn(r[6], r[7])));
}

// 16 blocks x 64 threads: code k = blockIdx*64 + tid. Writes SWIZZLED E.
__global__ __launch_bounds__(64) void vq_init(const float* __restrict__ emb,
                                              float* __restrict__ ws) {
    const int k = blockIdx.x * 64 + threadIdx.x;
    float row[DDIM];
    const float4* src = (const float4*)(emb + (size_t)k * DDIM);
    #pragma unroll
    for (int j = 0; j < 16; ++j) ((float4*)row)[j] = src[j];
    float C = np_pairwise_sumsq64(row);
    ws[WS_C + k] = C;
    {
        const int c = k >> 4, col = k & 15;
        uint32_t* eb = (uint32_t*)ws + WS_E + c * 512;   // chunk base (u32)
        #pragma unroll
        for (int q = 0; q < 4; ++q) {
            uint32_t* d0 = eb + (q * 16 + col) * 4;          // b0 plane
            uint32_t* d1 = eb + 256 + (q * 16 + col) * 4;    // b1 plane
            #pragma unroll
            for (int j = 0; j < 4; ++j) {
                d0[j] = pack2bf(row[q * 8 + 2 * j],      row[q * 8 + 2 * j + 1]);
                d1[j] = pack2bf(row[32 + q * 8 + 2 * j], row[32 + q * 8 + 2 * j + 1]);
            }
        }
    }
    float m = C;
    #pragma unroll
    for (int off = 32; off > 0; off >>= 1) m = fmaxf(m, __shfl_down(m, off, 64));
    if (threadIdx.x == 0) ws[WS_MAXC + blockIdx.x] = m;
    if (k == 0) ((uint32_t*)ws)[WS_CTR] = 0u;
}

__global__ __launch_bounds__(256, 4) void vq_main(
        const float* __restrict__ inp, const float* __restrict__ emb,
        float* __restrict__ ws, float* __restrict__ out)
{
    __shared__ float    sAp[PPB][4];    // pairwise partials (r2j + r2j+1)
    __shared__ float    sA[PPB];
    __shared__ float    sPart[4][PPB];
    __shared__ float    sThr[PPB];
    __shared__ uint16_t sCand[PPB * 4 * 8];
    __shared__ uint8_t  sCnt[PPB * 4];
    __shared__ int      sWin[PPB];
    __shared__ float    sred[4];
    __shared__ int      sLast;

    const int tid  = threadIdx.x;
    const int lane = tid & 63;
    const int wave = tid >> 6;          // = code quarter
    const int col  = lane & 15;
    const int quad = lane >> 4;
    const int base = blockIdx.x * PPB;
    const int b    = base >> 10;
    const int hw0  = base & 1023;

    // ---- prologue: exact-A partials, 4 threads per point (bit-exact tree
    //      split of np pairwise: this thread computes r_{2j}+r_{2j+1}) -------
    {
        const int pp = tid >> 2;            // point
        const int jj = (tid & 3) * 2;       // r-pair base
        const float* xin = inp + (size_t)b * DDIM * HW + (hw0 + pp);
        float r0, r1;
        {
            float v0 = xin[(size_t)jj * HW];
            float v1 = xin[(size_t)(jj + 1) * HW];
            r0 = __fmul_rn(v0, v0);
            r1 = __fmul_rn(v1, v1);
        }
        #pragma unroll
        for (int i = 8; i < 64; i += 8) {
            float v0 = xin[(size_t)(i + jj) * HW];
            float v1 = xin[(size_t)(i + jj + 1) * HW];
            r0 = __fadd_rn(r0, __fmul_rn(v0, v0));
            r1 = __fadd_rn(r1, __fmul_rn(v1, v1));
        }
        sAp[pp][tid & 3] = __fadd_rn(r0, r1);
    }

    // ---- A-fragments for 4 row-groups (r8/r11-verified layout) -------------
    short8v a[4][2];
    #pragma unroll
    for (int g = 0; g < 4; ++g) {
        const float* xp = inp + (size_t)b * DDIM * HW + (hw0 + g * 16 + col);
        short8v t0, t1;
        #pragma unroll
        for (int j = 0; j < 8; ++j) {
            t0[j] = (short)f2bf(xp[(size_t)(quad * 8 + j) * HW]);
            t1[j] = (short)f2bf(xp[(size_t)(32 + quad * 8 + j) * HW]);
        }
        a[g][0] = t0; a[g][1] = t1;
    }

    // swizzled E: lane reads its 16B at chunk*2048 + plane*1024 + lane*16 —
    // contiguous 1KB per wave-load (r17-proven 15% win).
    const char* Eb = (const char*)((const uint32_t*)ws + WS_E);
    const char* Ew = Eb + (size_t)wave * 16 * 2048 + (size_t)lane * 16;
    const float* Cw = ws + WS_C;
    const int k0 = wave * 256;

    // ---- sweep 1: per-point score-max, depth-2 pipelined loads -------------
    float smaxv[4][4];
    #pragma unroll
    for (int g = 0; g < 4; ++g)
        #pragma unroll
        for (int r = 0; r < 4; ++r) smaxv[g][r] = -3.0e38f;

    {
        short8v pa0 = *(const short8v*)(Ew);
        short8v pa1 = *(const short8v*)(Ew + 1024);
        short8v pb0 = *(const short8v*)(Ew + 2048);
        short8v pb1 = *(const short8v*)(Ew + 2048 + 1024);
        float   cia = Cw[k0 + col] * -0.5f;
        float   cib = Cw[k0 + 16 + col] * -0.5f;
        #pragma unroll 1
        for (int c2 = 0; c2 < 16; c2 += 2) {
            short8v u0 = pa0, u1 = pa1; float uci = cia;
            if (c2 + 2 < 16) {
                const char* er = Ew + (size_t)(c2 + 2) * 2048;
                pa0 = *(const short8v*)(er);
                pa1 = *(const short8v*)(er + 1024);
                cia = Cw[k0 + (c2 + 2) * 16 + col] * -0.5f;
            }
            float4v ci4 = {uci, uci, uci, uci};
            #pragma unroll
            for (int g = 0; g < 4; ++g) {
                float4v acc = ci4;
                acc = __builtin_amdgcn_mfma_f32_16x16x32_bf16(a[g][0], u0, acc, 0, 0, 0);
                acc = __builtin_amdgcn_mfma_f32_16x16x32_bf16(a[g][1], u1, acc, 0, 0, 0);
                #pragma unroll
                for (int r = 0; r < 4; ++r) smaxv[g][r] = fmaxf(smaxv[g][r], acc[r]);
            }
            short8v v0 = pb0, v1 = pb1; float vci = cib;
            if (c2 + 3 < 16) {
                const char* er = Ew + (size_t)(c2 + 3) * 2048;
                pb0 = *(const short8v*)(er);
                pb1 = *(const short8v*)(er + 1024);
                cib = Cw[k0 + (c2 + 3) * 16 + col] * -0.5f;
            }
            float4v ci4b = {vci, vci, vci, vci};
            #pragma unroll
            for (int g = 0; g < 4; ++g) {
                float4v acc = ci4b;
                acc = __builtin_amdgcn_mfma_f32_16x16x32_bf16(a[g][0], v0, acc, 0, 0, 0);
                acc = __builtin_amdgcn_mfma_f32_16x16x32_bf16(a[g][1], v1, acc, 0, 0, 0);
                #pragma unroll
                for (int r = 0; r < 4; ++r) smaxv[g][r] = fmaxf(smaxv[g][r], acc[r]);
            }
        }
    }
    #pragma unroll
    for (int g = 0; g < 4; ++g)
        #pragma unroll
        for (int r = 0; r < 4; ++r) {
            float m = smaxv[g][r];
            m = fmaxf(m, __shfl_xor(m, 1, 16));
            m = fmaxf(m, __shfl_xor(m, 2, 16));
            m = fmaxf(m, __shfl_xor(m, 4, 16));
            m = fmaxf(m, __shfl_xor(m, 8, 16));
            if (col == 0) sPart[wave][g * 16 + quad * 4 + r] = m;
        }
    __syncthreads();

    // ---- per-point threshold (also combine exact-A partials, exact tree) ---
    if (tid < PPB) {
        float A = __fadd_rn(__fadd_rn(sAp[tid][0], sAp[tid][1]),
                            __fadd_rn(sAp[tid][2], sAp[tid][3]));
        sA[tid] = A;
        float gm = fmaxf(fmaxf(sPart[0][tid], sPart[1][tid]),
                         fmaxf(sPart[2][tid], sPart[3][tid]));
        float mc = ws[WS_MAXC];
        #pragma unroll
        for (int j = 1; j < 16; ++j) mc = fmaxf(mc, ws[WS_MAXC + j]);
        sThr[tid] = gm - (0.015625f * sqrtf(A) * sqrtf(mc) + 6e-5f);
    }
    __syncthreads();

    float thr[4][4];
    #pragma unroll
    for (int g = 0; g < 4; ++g)
        #pragma unroll
        for (int r = 0; r < 4; ++r) thr[g][r] = sThr[g * 16 + quad * 4 + r];

    // ---- sweep 2: candidates (identical MFMA, depth-2 pipeline, ballot) ----
    int cnt[4][4];
    #pragma unroll
    for (int g = 0; g < 4; ++g)
        #pragma unroll
        for (int r = 0; r < 4; ++r) cnt[g][r] = 0;

    {
        short8v pa0 = *(const short8v*)(Ew);
        short8v pa1 = *(const short8v*)(Ew + 1024);
        short8v pb0 = *(const short8v*)(Ew + 2048);
        short8v pb1 = *(const short8v*)(Ew + 2048 + 1024);
        float   cia = Cw[k0 + col] * -0.5f;
        float   cib = Cw[k0 + 16 + col] * -0.5f;
        #pragma unroll 1
        for (int c2 = 0; c2 < 16; c2 += 2) {
            short8v u0 = pa0, u1 = pa1; float uci = cia;
            if (c2 + 2 < 16) {
                const char* er = Ew + (size_t)(c2 + 2) * 2048;
                pa0 = *(const short8v*)(er);
                pa1 = *(const short8v*)(er + 1024);
                cia = Cw[k0 + (c2 + 2) * 16 + col] * -0.5f;
            }
            float4v ci4 = {uci, uci, uci, uci};
            #pragma unroll
            for (int g = 0; g < 4; ++g) {
                float4v acc = ci4;
                acc = __builtin_amdgcn_mfma_f32_16x16x32_bf16(a[g][0], u0, acc, 0, 0, 0);
                acc = __builtin_amdgcn_mfma_f32_16x16x32_bf16(a[g][1], u1, acc, 0, 0, 0);
                #pragma unroll
                for (int r = 0; r < 4; ++r) {
                    unsigned long long bm = __ballot(acc[r] >= thr[g][r]);
                    if (col == 0) {
                        unsigned gm = (unsigned)(bm >> (quad * 16)) & 0xffffu;
                        while (gm) {
                            int bit = __ffs(gm) - 1;
                            gm &= gm - 1;
                            int ct = cnt[g][r];
                            if (ct < 8)
                                sCand[((g * 16 + quad * 4 + r) * 4 + wave) * 8 + ct] =
                                    (uint16_t)(k0 + c2 * 16 + bit);
                            cnt[g][r] = ct + 1;
                        }
                    }
                }
            }
            short8v v0 = pb0, v1 = pb1; float vci = cib;
            if (c2 + 3 < 16) {
                const char* er = Ew + (size_t)(c2 + 3) * 2048;
                pb0 = *(const short8v*)(er);
                pb1 = *(const short8v*)(er + 1024);
                cib = Cw[k0 + (c2 + 3) * 16 + col] * -0.5f;
            }
            float4v ci4b = {vci, vci, vci, vci};
            #pragma unroll
            for (int g = 0; g < 4; ++g) {
                float4v acc = ci4b;
                acc = __builtin_amdgcn_mfma_f32_16x16x32_bf16(a[g][0], v0, acc, 0, 0, 0);
                acc = __builtin_amdgcn_mfma_f32_16x16x32_bf16(a[g][1], v1, acc, 0, 0, 0);
                #pragma unroll
                for (int r = 0; r < 4; ++r) {
                    unsigned long long bm = __ballot(acc[r] >= thr[g][r]);
                    if (col == 0) {
                        unsigned gm = (unsigned)(bm >> (quad * 16)) & 0xffffu;
                        while (gm) {
                            int bit = __ffs(gm) - 1;
                            gm &= gm - 1;
                            int ct = cnt[g][r];
                            if (ct < 8)
                                sCand[((g * 16 + quad * 4 + r) * 4 + wave) * 8 + ct] =
                                    (uint16_t)(k0 + (c2 + 1) * 16 + bit);
                            cnt[g][r] = ct + 1;
                        }
                    }
                }
            }
        }
    }
    if (col == 0) {
        #pragma unroll
        for (int g = 0; g < 4; ++g)
            #pragma unroll
            for (int r = 0; r < 4; ++r) {
                int c = cnt[g][r];
                sCnt[(g * 16 + quad * 4 + r) * 4 + wave] = (uint8_t)(c > 255 ? 255 : c);
            }
    }
    __syncthreads();

    // ---- rescue: exact np-fp32 on candidates -------------------------------
    if (tid < PPB) {
        const int p = tid, n = base + p;
        int cq[4], tot = 0, cmax = 0;
        #pragma unroll
        for (int q = 0; q < 4; ++q) {
            cq[q] = sCnt[p * 4 + q];
            tot += cq[q];
            cmax = cq[q] > cmax ? cq[q] : cmax;
        }
        int win;
        if (tot == 1) {
            win = 0;
            #pragma unroll
            for (int q = 0; q < 4; ++q)
                if (cq[q]) win = sCand[(p * 4 + q) * 8];
        } else {
            const float* xin = inp + (size_t)b * DDIM * HW + (hw0 + p);
            float x[DDIM];
            #pragma unroll
            for (int d = 0; d < DDIM; ++d) x[d] = xin[(size_t)d * HW];
            const float A = sA[p];
            float bd = 3.0e38f; win = KCODES - 1;
            if (cmax <= 8) {
                #pragma unroll 1
                for (int q = 0; q < 4; ++q) {
                    #pragma unroll 1
                    for (int i = 0; i < cq[q]; ++i) {   // ascending k order
                        int k = sCand[(p * 4 + q) * 8 + i];
                        float e[DDIM];
                        const float4* e4 = (const float4*)(emb + (size_t)k * DDIM);
                        #pragma unroll
                        for (int j = 0; j < 16; ++j) ((float4*)e)[j] = e4[j];
                        float g = 0.f;
                        #pragma unroll
                        for (int d = 0; d < DDIM; ++d) g = fmaf(x[d], e[d], g);
                        float dd = __fadd_rn(__fsub_rn(A, __fmul_rn(2.0f, g)), Cw[k]);
                        if (dd < bd || (dd == bd && k < win)) { bd = dd; win = k; }
                    }
                }
            } else {                                    // overflow safety
                #pragma unroll 1
                for (int k = 0; k < KCODES; ++k) {
                    float e[DDIM];
                    const float4* e4 = (const float4*)(emb + (size_t)k * DDIM);
                    #pragma unroll
                    for (int j = 0; j < 16; ++j) ((float4*)e)[j] = e4[j];
                    float g = 0.f;
                    #pragma unroll
                    for (int d = 0; d < DDIM; ++d) g = fmaf(x[d], e[d], g);
                    float dd = __fadd_rn(__fsub_rn(A, __fmul_rn(2.0f, g)), Cw[k]);
                    if (dd < bd) { bd = dd; win = k; }
                }
            }
        }
        sWin[p] = win;
        out[OUT_IDX + n] = (float)win;
    }
    __syncthreads();

    // ---- epilogue: quantized NCHW + loss partial (plain store) -------------
    {
        const int pl = tid & 63, qtr = tid >> 6;
        const int win = sWin[pl];
        const int ch0 = qtr * 16;
        float q[16];
        const float4* q4 = (const float4*)(emb + (size_t)win * DDIM + ch0);
        #pragma unroll
        for (int j = 0; j < 4; ++j) ((float4*)q)[j] = q4[j];
        const size_t off = (size_t)b * DDIM * HW + (size_t)ch0 * HW + (hw0 + pl);
        const float* xin2 = inp + off;
        float* orow = out + off;
        float lacc = 0.f;
        #pragma unroll
        for (int j = 0; j < 16; ++j) {
            float xv = xin2[(size_t)j * HW];
            float diff = __fsub_rn(q[j], xv);
            orow[(size_t)j * HW] = __fadd_rn(xv, diff);   // ref's x + (q - x)
            lacc = fmaf(diff, diff, lacc);
        }
        #pragma unroll
        for (int o2 = 32; o2 > 0; o2 >>= 1) lacc += __shfl_down(lacc, o2, 64);
        if (lane == 0) sred[wave] = lacc;
    }
    __syncthreads();

    // ---- fin merged: last block reduces partials (identical add order) -----
    if (tid == 0) {
        ws[WS_PART + blockIdx.x] = sred[0] + sred[1] + sred[2] + sred[3];
        __threadfence();
        unsigned int old = atomicAdd((unsigned int*)ws + WS_CTR, 1u);
        sLast = (old == NBLK - 1) ? 1 : 0;
    }
    __syncthreads();
    if (sLast) {
        __threadfence();
        float s = 0.f;
        #pragma unroll
        for (int j = 0; j < 4; ++j) s += ws[WS_PART + j * 256 + tid];
        #pragma unroll
        for (int off = 32; off > 0; off >>= 1) s += __shfl_down(s, off, 64);
        if ((tid & 63) == 0) sred[tid >> 6] = s;
        __syncthreads();
        if (tid == 0) {
            float L = sred[0] + sred[1] + sred[2] + sred[3];
            out[OUT_LOSS] = L * (1.25f / 4194304.0f);   // (1+CC)*mean over N*D
            out[OUT_NLL]  = 1.0f;
        }
    }
}

extern "C" void kernel_launch(void* const* d_in, const int* in_sizes, int n_in,
                              void* d_out, int out_size, void* d_ws, size_t ws_size,
                              hipStream_t stream) {
    const float* inp = (const float*)d_in[0];
    const float* emb = (const float*)d_in[1];
    float* out = (float*)d_out;
    float* ws  = (float*)d_ws;

    vq_init<<<16, 64, 0, stream>>>(emb, ws);
    vq_main<<<NBLK, 256, 0, stream>>>(inp, emb, ws, out);
}

// Round 6
// 114.468 us; speedup vs baseline: 3.3027x; 1.2945x over previous
//
#include <hip/hip_runtime.h>
#include <stdint.h>

// VQ-VAE vector quantizer — fp32, NCHW input [64,64,32,32], emb [1024,64].
// r23: R5 isolated the hidden confounder — the merged-fin tail
// (__threadfence + device atomic) costs ~32us (L2 writeback on non-coherent
// XCDs; WRITE +3.1MB, FETCH +1.3MB per dispatch). It rode along in R1/R4/R5.
// Fix: back to THREE kernels (kernel boundary = free visibility, no fence).
// Core: R1's swapped-operand MFMA (D[code][point]) — re-scored as ~6us FASTER
// than the R0 core under equal fin-merge conditions (79.9 vs 85.3) — kept
// verbatim (absmax 0.0 in R1). Per-lane u64 candidate lists, no ballots.
constexpr int KCODES = 1024;
constexpr int DDIM   = 64;
constexpr int HW     = 1024;
constexpr int NPTS   = 65536;
constexpr int PPB    = 64;            // points per block
constexpr int NBLK   = NPTS / PPB;    // 1024

constexpr int OUT_IDX  = 4194304;
constexpr int OUT_LOSS = 4259840;
constexpr int OUT_NLL  = 4259841;

// ws 32-bit-unit offsets
constexpr int WS_MAXC  = 0;       // 16 f  : per-init-block max C
constexpr int WS_C     = 16;      // 1024 f: exact np C_k
constexpr int WS_E     = 2048;    // 32768 u32: SWIZZLED bf16-E (64 chunks x 2KB)
constexpr int WS_PART  = 34816;   // 1024 f: per-block loss partials

typedef __attribute__((ext_vector_type(8))) short short8v;
typedef __attribute__((ext_vector_type(4))) float float4v;

__device__ __forceinline__ uint16_t f2bf(float f) {   // RNE fp32->bf16
    uint32_t u = __float_as_uint(f);
    return (uint16_t)((u + 0x7fffu + ((u >> 16) & 1u)) >> 16);
}
__device__ __forceinline__ uint32_t pack2bf(float a, float b) {
    return (uint32_t)f2bf(a) | ((uint32_t)f2bf(b) << 16);
}

__device__ __forceinline__ float np_pairwise_sumsq64(const float* a) {
    float r[8];
    #pragma unroll
    for (int j = 0; j < 8; ++j) r[j] = __fmul_rn(a[j], a[j]);
    #pragma unroll
    for (int i = 8; i < 64; i += 8)
        #pragma unroll
        for (int j = 0; j < 8; ++j)
            r[j] = __fadd_rn(r[j], __fmul_rn(a[i + j], a[i + j]));
    return __fadd_rn(__fadd_rn(__fadd_rn(r[0], r[1]), __fadd_rn(r[2], r[3])),
                     __fadd_rn(__fadd_rn(r[4], r[5]), __fadd_rn(r[6], r[7])));
}

// 16 blocks x 64 threads: code k = blockIdx*64 + tid. Writes SWIZZLED E.
__global__ __launch_bounds__(64) void vq_init(const float* __restrict__ emb,
                                              float* __restrict__ ws) {
    const int k = blockIdx.x * 64 + threadIdx.x;
    float row[DDIM];
    const float4* src = (const float4*)(emb + (size_t)k * DDIM);
    #pragma unroll
    for (int j = 0; j < 16; ++j) ((float4*)row)[j] = src[j];
    float C = np_pairwise_sumsq64(row);
    ws[WS_C + k] = C;
    {
        const int c = k >> 4, col = k & 15;
        uint32_t* eb = (uint32_t*)ws + WS_E + c * 512;   // chunk base (u32)
        #pragma unroll
        for (int q = 0; q < 4; ++q) {
            uint32_t* d0 = eb + (q * 16 + col) * 4;          // b0 plane
            uint32_t* d1 = eb + 256 + (q * 16 + col) * 4;    // b1 plane
            #pragma unroll
            for (int j = 0; j < 4; ++j) {
                d0[j] = pack2bf(row[q * 8 + 2 * j],      row[q * 8 + 2 * j + 1]);
                d1[j] = pack2bf(row[32 + q * 8 + 2 * j], row[32 + q * 8 + 2 * j + 1]);
            }
        }
    }
    float m = C;
    #pragma unroll
    for (int off = 32; off > 0; off >>= 1) m = fmaxf(m, __shfl_down(m, off, 64));
    if (threadIdx.x == 0) ws[WS_MAXC + blockIdx.x] = m;
}

__global__ __launch_bounds__(256, 4) void vq_main(
        const float* __restrict__ inp, const float* __restrict__ emb,
        float* __restrict__ ws, float* __restrict__ out)
{
    __shared__ float    sAp[PPB][4];    // pairwise partials (r2j + r2j+1)
    __shared__ float    sA[PPB];
    __shared__ float    sPart[4][PPB];
    __shared__ float    sThr[PPB];
    __shared__ unsigned long long sCandL[16][PPB];  // [wave*4+quad][point]
    __shared__ int      sCntL[16][PPB];
    __shared__ int      sWin[PPB];
    __shared__ float    sred[4];

    const int tid  = threadIdx.x;
    const int lane = tid & 63;
    const int wave = tid >> 6;          // = code quarter
    const int col  = lane & 15;         // = POINT within 16-group (swapped layout)
    const int quad = lane >> 4;         // = code sub-quad (rows quad*4+r)
    const int base = blockIdx.x * PPB;
    const int b    = base >> 10;
    const int hw0  = base & 1023;

    // ---- prologue: exact-A partials, 4 threads per point (bit-exact tree
    //      split of np pairwise: this thread computes r_{2j}+r_{2j+1}) -------
    {
        const int pp = tid >> 2;            // point
        const int jj = (tid & 3) * 2;       // r-pair base
        const float* xin = inp + (size_t)b * DDIM * HW + (hw0 + pp);
        float r0, r1;
        {
            float v0 = xin[(size_t)jj * HW];
            float v1 = xin[(size_t)(jj + 1) * HW];
            r0 = __fmul_rn(v0, v0);
            r1 = __fmul_rn(v1, v1);
        }
        #pragma unroll
        for (int i = 8; i < 64; i += 8) {
            float v0 = xin[(size_t)(i + jj) * HW];
            float v1 = xin[(size_t)(i + jj + 1) * HW];
            r0 = __fadd_rn(r0, __fmul_rn(v0, v0));
            r1 = __fadd_rn(r1, __fmul_rn(v1, v1));
        }
        sAp[pp][tid & 3] = __fadd_rn(r0, r1);
    }

    // ---- X-fragments for 4 row-groups (unchanged; reused as MFMA B-op) ----
    short8v a[4][2];
    #pragma unroll
    for (int g = 0; g < 4; ++g) {
        const float* xp = inp + (size_t)b * DDIM * HW + (hw0 + g * 16 + col);
        short8v t0, t1;
        #pragma unroll
        for (int j = 0; j < 8; ++j) {
            t0[j] = (short)f2bf(xp[(size_t)(quad * 8 + j) * HW]);
            t1[j] = (short)f2bf(xp[(size_t)(32 + quad * 8 + j) * HW]);
        }
        a[g][0] = t0; a[g][1] = t1;
    }

    // swizzled E: lane reads its 16B at chunk*2048 + plane*1024 + lane*16 —
    // contiguous 1KB per wave-load; lane&15 indexes CODE -> valid A-fragment.
    const char* Eb = (const char*)((const uint32_t*)ws + WS_E);
    const char* Ew = Eb + (size_t)wave * 16 * 2048 + (size_t)lane * 16;
    const float* Cw = ws + WS_C;
    const int k0 = wave * 256;
    const float4v* Cq = (const float4v*)(ws + WS_C + k0);   // 16B-aligned

    // ---- sweep 1: per-point score-max, per-lane (no shuffles in loop) -----
    float gmax[4] = {-3.0e38f, -3.0e38f, -3.0e38f, -3.0e38f};
    {
        short8v pa0 = *(const short8v*)(Ew);
        short8v pa1 = *(const short8v*)(Ew + 1024);
        short8v pb0 = *(const short8v*)(Ew + 2048);
        short8v pb1 = *(const short8v*)(Ew + 3072);
        float4v ca4 = Cq[quad];
        float4v cb4 = Cq[4 + quad];
        #pragma unroll 1
        for (int c2 = 0; c2 < 16; c2 += 2) {
            short8v u0 = pa0, u1 = pa1; float4v uc4 = ca4;
            if (c2 + 2 < 16) {
                const char* er = Ew + (size_t)(c2 + 2) * 2048;
                pa0 = *(const short8v*)(er);
                pa1 = *(const short8v*)(er + 1024);
                ca4 = Cq[(c2 + 2) * 4 + quad];
            }
            {
                float4v ci = {uc4[0] * -0.5f, uc4[1] * -0.5f,
                              uc4[2] * -0.5f, uc4[3] * -0.5f};
                #pragma unroll
                for (int g = 0; g < 4; ++g) {
                    float4v acc = ci;
                    acc = __builtin_amdgcn_mfma_f32_16x16x32_bf16(u0, a[g][0], acc, 0, 0, 0);
                    acc = __builtin_amdgcn_mfma_f32_16x16x32_bf16(u1, a[g][1], acc, 0, 0, 0);
                    gmax[g] = fmaxf(gmax[g],
                                    fmaxf(fmaxf(acc[0], acc[1]), fmaxf(acc[2], acc[3])));
                }
            }
            short8v v0 = pb0, v1 = pb1; float4v vc4 = cb4;
            if (c2 + 3 < 16) {
                const char* er = Ew + (size_t)(c2 + 3) * 2048;
                pb0 = *(const short8v*)(er);
                pb1 = *(const short8v*)(er + 1024);
                cb4 = Cq[(c2 + 3) * 4 + quad];
            }
            {
                float4v ci = {vc4[0] * -0.5f, vc4[1] * -0.5f,
                              vc4[2] * -0.5f, vc4[3] * -0.5f};
                #pragma unroll
                for (int g = 0; g < 4; ++g) {
                    float4v acc = ci;
                    acc = __builtin_amdgcn_mfma_f32_16x16x32_bf16(v0, a[g][0], acc, 0, 0, 0);
                    acc = __builtin_amdgcn_mfma_f32_16x16x32_bf16(v1, a[g][1], acc, 0, 0, 0);
                    gmax[g] = fmaxf(gmax[g],
                                    fmaxf(fmaxf(acc[0], acc[1]), fmaxf(acc[2], acc[3])));
                }
            }
        }
    }
    // cross-quad reduce: 2 shuffles (was a 64-shuffle tree)
    #pragma unroll
    for (int g = 0; g < 4; ++g) {
        float m = gmax[g];
        m = fmaxf(m, __shfl_xor(m, 16, 64));
        m = fmaxf(m, __shfl_xor(m, 32, 64));
        if (quad == 0) sPart[wave][g * 16 + col] = m;
    }
    __syncthreads();

    // ---- per-point threshold (also combine exact-A partials, exact tree) ---
    if (tid < PPB) {
        float A = __fadd_rn(__fadd_rn(sAp[tid][0], sAp[tid][1]),
                            __fadd_rn(sAp[tid][2], sAp[tid][3]));
        sA[tid] = A;
        float gm = fmaxf(fmaxf(sPart[0][tid], sPart[1][tid]),
                         fmaxf(sPart[2][tid], sPart[3][tid]));
        float mc = ws[WS_MAXC];
        #pragma unroll
        for (int j = 1; j < 16; ++j) mc = fmaxf(mc, ws[WS_MAXC + j]);
        sThr[tid] = gm - (0.015625f * sqrtf(A) * sqrtf(mc) + 6e-5f);
    }
    __syncthreads();

    float thrg[4];
    #pragma unroll
    for (int g = 0; g < 4; ++g) thrg[g] = sThr[g * 16 + col];

    // ---- sweep 2: candidates via per-lane u64 register lists ---------------
    unsigned long long lst[4] = {0ull, 0ull, 0ull, 0ull};
    int cnt[4] = {0, 0, 0, 0};
    {
        short8v pa0 = *(const short8v*)(Ew);
        short8v pa1 = *(const short8v*)(Ew + 1024);
        short8v pb0 = *(const short8v*)(Ew + 2048);
        short8v pb1 = *(const short8v*)(Ew + 3072);
        float4v ca4 = Cq[quad];
        float4v cb4 = Cq[4 + quad];
        #pragma unroll 1
        for (int c2 = 0; c2 < 16; c2 += 2) {
            short8v u0 = pa0, u1 = pa1; float4v uc4 = ca4;
            if (c2 + 2 < 16) {
                const char* er = Ew + (size_t)(c2 + 2) * 2048;
                pa0 = *(const short8v*)(er);
                pa1 = *(const short8v*)(er + 1024);
                ca4 = Cq[(c2 + 2) * 4 + quad];
            }
            {
                float4v ci = {uc4[0] * -0.5f, uc4[1] * -0.5f,
                              uc4[2] * -0.5f, uc4[3] * -0.5f};
                const int kb = k0 + c2 * 16 + quad * 4;
                #pragma unroll
                for (int g = 0; g < 4; ++g) {
                    float4v acc = ci;
                    acc = __builtin_amdgcn_mfma_f32_16x16x32_bf16(u0, a[g][0], acc, 0, 0, 0);
                    acc = __builtin_amdgcn_mfma_f32_16x16x32_bf16(u1, a[g][1], acc, 0, 0, 0);
                    float m4 = fmaxf(fmaxf(acc[0], acc[1]), fmaxf(acc[2], acc[3]));
                    if (__any(m4 >= thrg[g])) {
                        #pragma unroll
                        for (int r = 0; r < 4; ++r) {
                            if (acc[r] >= thrg[g]) {
                                if (cnt[g] < 4)
                                    lst[g] |= (unsigned long long)(unsigned)(kb + r)
                                              << (cnt[g] << 4);
                                ++cnt[g];
                            }
                        }
                    }
                }
            }
            short8v v0 = pb0, v1 = pb1; float4v vc4 = cb4;
            if (c2 + 3 < 16) {
                const char* er = Ew + (size_t)(c2 + 3) * 2048;
                pb0 = *(const short8v*)(er);
                pb1 = *(const short8v*)(er + 1024);
                cb4 = Cq[(c2 + 3) * 4 + quad];
            }
            {
                float4v ci = {vc4[0] * -0.5f, vc4[1] * -0.5f,
                              vc4[2] * -0.5f, vc4[3] * -0.5f};
                const int kb = k0 + (c2 + 1) * 16 + quad * 4;
                #pragma unroll
                for (int g = 0; g < 4; ++g) {
                    float4v acc = ci;
                    acc = __builtin_amdgcn_mfma_f32_16x16x32_bf16(v0, a[g][0], acc, 0, 0, 0);
                    acc = __builtin_amdgcn_mfma_f32_16x16x32_bf16(v1, a[g][1], acc, 0, 0, 0);
                    float m4 = fmaxf(fmaxf(acc[0], acc[1]), fmaxf(acc[2], acc[3]));
                    if (__any(m4 >= thrg[g])) {
                        #pragma unroll
                        for (int r = 0; r < 4; ++r) {
                            if (acc[r] >= thrg[g]) {
                                if (cnt[g] < 4)
                                    lst[g] |= (unsigned long long)(unsigned)(kb + r)
                                              << (cnt[g] << 4);
                                ++cnt[g];
                            }
                        }
                    }
                }
            }
        }
    }
    {
        const int wq = wave * 4 + quad;
        #pragma unroll
        for (int g = 0; g < 4; ++g) {
            sCandL[wq][g * 16 + col] = lst[g];
            sCntL[wq][g * 16 + col]  = cnt[g];
        }
    }
    __syncthreads();

    // ---- rescue: exact np-fp32 on candidates -------------------------------
    if (tid < PPB) {
        const int p = tid, n = base + p;
        int tot = 0, cmax = 0;
        #pragma unroll
        for (int wq = 0; wq < 16; ++wq) {
            int c = sCntL[wq][p];
            tot += c;
            cmax = c > cmax ? c : cmax;
        }
        int win;
        if (tot == 1) {
            win = 0;
            #pragma unroll
            for (int wq = 0; wq < 16; ++wq)
                if (sCntL[wq][p]) win = (int)(sCandL[wq][p] & 0xffffu);
        } else {
            const float* xin = inp + (size_t)b * DDIM * HW + (hw0 + p);
            float x[DDIM];
            #pragma unroll
            for (int d = 0; d < DDIM; ++d) x[d] = xin[(size_t)d * HW];
            const float A = sA[p];
            float bd = 3.0e38f; win = KCODES - 1;
            if (cmax <= 4) {
                #pragma unroll 1
                for (int wq = 0; wq < 16; ++wq) {
                    int c = sCntL[wq][p];
                    unsigned long long L = sCandL[wq][p];
                    #pragma unroll 1
                    for (int i = 0; i < c; ++i) {
                        int k = (int)(L & 0xffffu);
                        L >>= 16;
                        float e[DDIM];
                        const float4* e4 = (const float4*)(emb + (size_t)k * DDIM);
                        #pragma unroll
                        for (int j = 0; j < 16; ++j) ((float4*)e)[j] = e4[j];
                        float g = 0.f;
                        #pragma unroll
                        for (int d = 0; d < DDIM; ++d) g = fmaf(x[d], e[d], g);
                        float dd = __fadd_rn(__fsub_rn(A, __fmul_rn(2.0f, g)), Cw[k]);
                        if (dd < bd || (dd == bd && k < win)) { bd = dd; win = k; }
                    }
                }
            } else {                                    // overflow safety
                #pragma unroll 1
                for (int k = 0; k < KCODES; ++k) {
                    float e[DDIM];
                    const float4* e4 = (const float4*)(emb + (size_t)k * DDIM);
                    #pragma unroll
                    for (int j = 0; j < 16; ++j) ((float4*)e)[j] = e4[j];
                    float g = 0.f;
                    #pragma unroll
                    for (int d = 0; d < DDIM; ++d) g = fmaf(x[d], e[d], g);
                    float dd = __fadd_rn(__fsub_rn(A, __fmul_rn(2.0f, g)), Cw[k]);
                    if (dd < bd) { bd = dd; win = k; }
                }
            }
        }
        sWin[p] = win;
        out[OUT_IDX + n] = (float)win;
    }
    __syncthreads();

    // ---- epilogue: quantized NCHW + loss partial (plain store) -------------
    {
        const int pl = tid & 63, qtr = tid >> 6;
        const int win = sWin[pl];
        const int ch0 = qtr * 16;
        float q[16];
        const float4* q4 = (const float4*)(emb + (size_t)win * DDIM + ch0);
        #pragma unroll
        for (int j = 0; j < 4; ++j) ((float4*)q)[j] = q4[j];
        const size_t off = (size_t)b * DDIM * HW + (size_t)ch0 * HW + (hw0 + pl);
        const float* xin2 = inp + off;
        float* orow = out + off;
        float lacc = 0.f;
        #pragma unroll
        for (int j = 0; j < 16; ++j) {
            float xv = xin2[(size_t)j * HW];
            float diff = __fsub_rn(q[j], xv);
            orow[(size_t)j * HW] = __fadd_rn(xv, diff);   // ref's x + (q - x)
            lacc = fmaf(diff, diff, lacc);
        }
        #pragma unroll
        for (int o2 = 32; o2 > 0; o2 >>= 1) lacc += __shfl_down(lacc, o2, 64);
        if (lane == 0) sred[wave] = lacc;
    }
    __syncthreads();
    if (tid == 0)
        ws[WS_PART + blockIdx.x] = sred[0] + sred[1] + sred[2] + sred[3];
}

// 1 block x 256: reduce 1024 partials -> loss; write nll
__global__ __launch_bounds__(256) void vq_fin(const float* __restrict__ ws,
                                              float* __restrict__ out) {
    __shared__ float sred[4];
    const int tid = threadIdx.x;
    float s = 0.f;
    #pragma unroll
    for (int j = 0; j < 4; ++j) s += ws[WS_PART + j * 256 + tid];
    #pragma unroll
    for (int off = 32; off > 0; off >>= 1) s += __shfl_down(s, off, 64);
    if ((tid & 63) == 0) sred[tid >> 6] = s;
    __syncthreads();
    if (tid == 0) {
        float L = sred[0] + sred[1] + sred[2] + sred[3];
        out[OUT_LOSS] = L * (1.25f / 4194304.0f);   // (1+CC)*mean over N*D
        out[OUT_NLL]  = 1.0f;
    }
}

extern "C" void kernel_launch(void* const* d_in, const int* in_sizes, int n_in,
                              void* d_out, int out_size, void* d_ws, size_t ws_size,
                              hipStream_t stream) {
    const float* inp = (const float*)d_in[0];
    const float* emb = (const float*)d_in[1];
    float* out = (float*)d_out;
    float* ws  = (float*)d_ws;

    vq_init<<<16, 64, 0, stream>>>(emb, ws);
    vq_main<<<NBLK, 256, 0, stream>>>(inp, emb, ws, out);
    vq_fin<<<1, 256, 0, stream>>>(ws, out);
}